// Round 9
// baseline (1224.024 us; speedup 1.0000x reference)
//
#include <hip/hip_runtime.h>
#include <hip/hip_bf16.h>

#define NEG_SLOPE 0.2f
#define EPB 4096  // edges per block in bucket phases

typedef __attribute__((ext_vector_type(8))) short short8;
typedef __attribute__((ext_vector_type(4))) float f32x4;

__device__ __forceinline__ unsigned short f2bf(float x) {
    unsigned u = __float_as_uint(x);
    unsigned r = (u + 0x7FFFu + ((u >> 16) & 1u)) >> 16;  // RNE
    return (unsigned short)r;
}

// =================== CSR build: two-level counting sort ===================

__global__ __launch_bounds__(256) void bucket_hist_k(
    const int* __restrict__ dsts, int* __restrict__ bcnt, int E, int Etot,
    int nbuck) {
    __shared__ int lh[512];
    for (int i = threadIdx.x; i < nbuck; i += 256) lh[i] = 0;
    __syncthreads();
    int base = blockIdx.x * EPB;
    int cnt = Etot - base;
    if (cnt > EPB) cnt = EPB;
    for (int i = threadIdx.x; i < cnt; i += 256) {
        int e = base + i;
        int d = (e < E) ? dsts[e] : (e - E);
        atomicAdd(&lh[d >> 8], 1);
    }
    __syncthreads();
    for (int i = threadIdx.x; i < nbuck; i += 256) {
        int c = lh[i];
        if (c) atomicAdd(&bcnt[i], c);
    }
}

__global__ __launch_bounds__(512) void bucket_scan_k(
    const int* __restrict__ bcnt, int* __restrict__ bptr,
    int* __restrict__ bcur, int nbuck, int Etot) {
    __shared__ int tmp[512];
    int t = threadIdx.x;
    int v = (t < nbuck) ? bcnt[t] : 0;
    tmp[t] = v;
    __syncthreads();
    for (int off = 1; off < 512; off <<= 1) {
        int x = (t >= off) ? tmp[t - off] : 0;
        __syncthreads();
        tmp[t] += x;
        __syncthreads();
    }
    int excl = tmp[t] - v;
    if (t < nbuck) { bptr[t] = excl; bcur[t] = excl; }
    if (t == 0) bptr[nbuck] = Etot;
}

__global__ __launch_bounds__(256) void bucket_scatter_k(
    const int* __restrict__ srcs, const int* __restrict__ dsts,
    int* __restrict__ bcur, int2* __restrict__ pairs, int E, int Etot,
    int nbuck) {
    __shared__ int lh[512];
    __shared__ int lbase[512];
    for (int i = threadIdx.x; i < nbuck; i += 256) lh[i] = 0;
    __syncthreads();
    int base = blockIdx.x * EPB;
    int cnt = Etot - base;
    if (cnt > EPB) cnt = EPB;
    for (int i = threadIdx.x; i < cnt; i += 256) {
        int e = base + i;
        int d = (e < E) ? dsts[e] : (e - E);
        atomicAdd(&lh[d >> 8], 1);
    }
    __syncthreads();
    for (int i = threadIdx.x; i < nbuck; i += 256) {
        int c = lh[i];
        lbase[i] = c ? atomicAdd(&bcur[i], c) : 0;
    }
    __syncthreads();
    for (int i = threadIdx.x; i < nbuck; i += 256) lh[i] = 0;
    __syncthreads();
    for (int i = threadIdx.x; i < cnt; i += 256) {
        int e = base + i;
        int s, d;
        if (e < E) { s = srcs[e]; d = dsts[e]; }
        else       { s = e - E;   d = s; }
        int b = d >> 8;
        int off = atomicAdd(&lh[b], 1);
        pairs[lbase[b] + off] = make_int2(s, d);
    }
}

__global__ __launch_bounds__(256) void bucket_sort_k(
    const int2* __restrict__ pairs, const int* __restrict__ bptr,
    int* __restrict__ row_ptr, int* __restrict__ csr_src, int N, int Etot,
    int nbuck) {
    __shared__ int lh[256];
    __shared__ int lscan[256];
    int b = blockIdx.x;
    int n0 = b << 8;
    int e0 = bptr[b], e1 = bptr[b + 1];
    int t = threadIdx.x;
    lh[t] = 0;
    __syncthreads();
    for (int e = e0 + t; e < e1; e += 256)
        atomicAdd(&lh[pairs[e].y - n0], 1);
    __syncthreads();
    int v = lh[t];
    lscan[t] = v;
    __syncthreads();
    for (int off = 1; off < 256; off <<= 1) {
        int x = (t >= off) ? lscan[t - off] : 0;
        __syncthreads();
        lscan[t] += x;
        __syncthreads();
    }
    int start = e0 + lscan[t] - v;
    int n = n0 + t;
    if (n < N) row_ptr[n] = start;
    lh[t] = start;  // reuse as cursor
    __syncthreads();
    for (int e = e0 + t; e < e1; e += 256) {
        int2 p = pairs[e];
        int pos = atomicAdd(&lh[p.y - n0], 1);
        csr_src[pos] = p.x;
    }
    if (b == nbuck - 1 && t == 0) row_ptr[N] = Etot;
}

// =================== MFMA GEMM: [N,K] fp32 @ [K,COUT] fp32 -> [N,COUT] ====

template <int K, int COUT>
__global__ __launch_bounds__(256) void gemm_mfma_k(
    const float* __restrict__ x, const float* __restrict__ W,
    float* __restrict__ out, int N) {
    constexpr int NT = (COUT + 15) / 16;
    constexpr int KT = K / 32;
    __shared__ alignas(16) short Wf[KT * NT * 64 * 8];
    int tid = threadIdx.x;
    for (int f = tid; f < KT * NT * 64; f += 256) {
        int lane = f & 63;
        int ntk = f >> 6;
        int nt = ntk % NT, kt = ntk / NT;
        int q = lane >> 4, c = lane & 15;
        int n = nt * 16 + c;
        int k0 = kt * 32 + q * 8;
        short8 frag;
        #pragma unroll
        for (int j = 0; j < 8; ++j) {
            float v = (n < COUT) ? W[(size_t)(k0 + j) * COUT + n] : 0.f;
            frag[j] = (short)f2bf(v);
        }
        *(short8*)&Wf[f * 8] = frag;
    }
    __syncthreads();
    int wave = tid >> 6, lane = tid & 63;
    int q = lane >> 4, c = lane & 15;
    int m0 = blockIdx.x * 64 + wave * 16;
    int arow = m0 + c;
    int arl = arow < N ? arow : N - 1;
    f32x4 acc[NT] = {};
    for (int kt = 0; kt < KT; ++kt) {
        const float* xp = x + (size_t)arl * K + kt * 32 + q * 8;
        float4 a0 = *(const float4*)xp;
        float4 a1 = *(const float4*)(xp + 4);
        float av[8] = {a0.x, a0.y, a0.z, a0.w, a1.x, a1.y, a1.z, a1.w};
        short8 af;
        #pragma unroll
        for (int j = 0; j < 8; ++j) af[j] = (short)f2bf(av[j]);
        #pragma unroll
        for (int nt = 0; nt < NT; ++nt) {
            short8 bf = *(const short8*)&Wf[((kt * NT + nt) * 64 + lane) * 8];
            acc[nt] = __builtin_amdgcn_mfma_f32_16x16x32_bf16(af, bf, acc[nt],
                                                              0, 0, 0);
        }
    }
    int orow = m0 + q * 4;
    #pragma unroll
    for (int nt = 0; nt < NT; ++nt) {
        int n = nt * 16 + c;
        if ((COUT % 16) && n >= COUT) continue;
        #pragma unroll
        for (int reg = 0; reg < 4; ++reg) {
            int r = orow + reg;
            if (r < N) out[(size_t)r * COUT + n] = acc[nt][reg];
        }
    }
}

// ======= pack kernel, width 64: att logits + bf16 record (192 B) ==========
// rec[n]: [0..127] 64 x bf16 h ; [128..159] 8 x fp32 as

__global__ __launch_bounds__(256) void pack8_k(
    const float* __restrict__ h, const float* __restrict__ a_src,
    const float* __restrict__ a_dst, char* __restrict__ rec,
    float* __restrict__ adb, int N) {
    int idx = blockIdx.x * 256 + threadIdx.x;
    if (idx >= N * 8) return;
    int n = idx >> 3, hd = idx & 7;
    const float* hp = h + (size_t)n * 64 + hd * 8;
    float4 h0 = *(const float4*)hp;
    float4 h1 = *(const float4*)(hp + 4);
    float as = h0.x * a_src[hd * 8 + 0] + h0.y * a_src[hd * 8 + 1] +
               h0.z * a_src[hd * 8 + 2] + h0.w * a_src[hd * 8 + 3] +
               h1.x * a_src[hd * 8 + 4] + h1.y * a_src[hd * 8 + 5] +
               h1.z * a_src[hd * 8 + 6] + h1.w * a_src[hd * 8 + 7];
    float ad = h0.x * a_dst[hd * 8 + 0] + h0.y * a_dst[hd * 8 + 1] +
               h0.z * a_dst[hd * 8 + 2] + h0.w * a_dst[hd * 8 + 3] +
               h1.x * a_dst[hd * 8 + 4] + h1.y * a_dst[hd * 8 + 5] +
               h1.z * a_dst[hd * 8 + 6] + h1.w * a_dst[hd * 8 + 7];
    adb[idx] = ad;
    char* r = rec + (size_t)n * 192;
    float hv[8] = {h0.x, h0.y, h0.z, h0.w, h1.x, h1.y, h1.z, h1.w};
    unsigned short u[8];
    #pragma unroll
    for (int j = 0; j < 8; ++j) u[j] = f2bf(hv[j]);
    uint4 pk;
    pk.x = (unsigned)u[0] | ((unsigned)u[1] << 16);
    pk.y = (unsigned)u[2] | ((unsigned)u[3] << 16);
    pk.z = (unsigned)u[4] | ((unsigned)u[5] << 16);
    pk.w = (unsigned)u[6] | ((unsigned)u[7] << 16);
    *(uint4*)(r + hd * 16) = pk;
    *(float*)(r + 128 + hd * 4) = as;
}

// ======= pack kernel, width 40 (H=1): record 128 B ==========

__global__ __launch_bounds__(256) void pack40_k(
    const float* __restrict__ h, const float* __restrict__ a_src,
    const float* __restrict__ a_dst, char* __restrict__ rec,
    float* __restrict__ adb, int N) {
    int node = blockIdx.x * 4 + (threadIdx.x >> 6);
    if (node >= N) return;
    int lane = threadIdx.x & 63;
    float hv = 0.f, pas = 0.f, pad = 0.f;
    if (lane < 40) {
        hv = h[(size_t)node * 40 + lane];
        pas = hv * a_src[lane];
        pad = hv * a_dst[lane];
    }
    #pragma unroll
    for (int off = 32; off > 0; off >>= 1) {
        pas += __shfl_xor(pas, off);
        pad += __shfl_xor(pad, off);
    }
    char* r = rec + (size_t)node * 128;
    if (lane < 40)
        *(unsigned short*)(r + lane * 2) = f2bf(hv);
    if (lane == 0) {
        *(float*)(r + 80) = pas;
        adb[node] = pad;
    }
}

// ======= aggregation, width 64: weight phase + fma phase ======
// weight phase: lane = (edge e_w = lane>>3, head hd_w = lane&7); 8 passes
// cover 64 edges x 8 heads. fma phase: lane = channel; weights via shuffle.

__global__ __launch_bounds__(256) void aggr64_k(
    const char* __restrict__ rec, const float* __restrict__ adb,
    const int* __restrict__ row_ptr, const int* __restrict__ csr_src,
    const float* __restrict__ bias, float* __restrict__ out, int N) {
    int node = blockIdx.x * 4 + (threadIdx.x >> 6);
    if (node >= N) return;
    int lane = threadIdx.x & 63;
    int hd_f = lane >> 3;   // fma-phase head
    int hd_w = lane & 7;    // weight-phase head
    int e_w  = lane >> 3;   // weight-phase edge sub-index
    int beg = row_ptr[node], end = row_ptr[node + 1];
    float ad_w = adb[node * 8 + hd_w];
    float acc = 0.f, lpart = 0.f;
    for (int i0 = beg; i0 < end; i0 += 64) {
        int tail = end - i0;
        int cnt = tail < 64 ? tail : 64;
        int sv = csr_src[i0 + (lane < tail ? lane : 0)];
        // ---- weight phase ----
        float wreg[8];
        #pragma unroll
        for (int p = 0; p < 8; ++p) {
            int j = p * 8 + e_w;
            int s = __shfl(sv, j);
            float as = *(const float*)(rec + (size_t)s * 192 + 128 + hd_w * 4);
            float v = as + ad_w;
            v = fmaxf(v, NEG_SLOPE * v);
            float w = __expf(v);
            w = (j < cnt) ? w : 0.f;
            wreg[p] = w;
            lpart += w;
        }
        // ---- fma phase ----
        #pragma unroll
        for (int p = 0; p < 8; ++p) {
            if (p * 8 >= cnt) break;          // wave-uniform
            int lim = cnt - p * 8;
            lim = lim > 8 ? 8 : lim;
            #pragma unroll
            for (int e = 0; e < 8; ++e) {
                if (e >= lim) break;          // wave-uniform
                int s = __shfl(sv, p * 8 + e);
                float w = __shfl(wreg[p], e * 8 + hd_f);
                unsigned u =
                    *(const unsigned short*)(rec + (size_t)s * 192 + lane * 2);
                acc = fmaf(w, __uint_as_float(u << 16), acc);
            }
        }
    }
    // l[hd] = sum of lpart over lanes with lane&7 == hd
    lpart += __shfl_xor(lpart, 8);
    lpart += __shfl_xor(lpart, 16);
    lpart += __shfl_xor(lpart, 32);
    float l = __shfl(lpart, hd_f);  // lane hd_f holds head hd_f
    out[(size_t)node * 64 + lane] = acc / (l + 1e-16f) + bias[lane];
}

// ======= aggregation, width 40 (H=1): weight phase + fma phase ======

__global__ __launch_bounds__(256) void aggr40_k(
    const char* __restrict__ rec, const float* __restrict__ adb,
    const int* __restrict__ row_ptr, const int* __restrict__ csr_src,
    float* __restrict__ out, int N) {
    int node = blockIdx.x * 4 + (threadIdx.x >> 6);
    if (node >= N) return;
    int lane = threadIdx.x & 63;
    int cl2 = (lane < 40 ? lane : 0) * 2;
    int beg = row_ptr[node], end = row_ptr[node + 1];
    float ad = adb[node];
    float acc = 0.f, lpart = 0.f;
    for (int i0 = beg; i0 < end; i0 += 64) {
        int tail = end - i0;
        int cnt = tail < 64 ? tail : 64;
        int sv = csr_src[i0 + (lane < tail ? lane : 0)];
        // ---- weight phase: one pass, lane = edge ----
        float as = *(const float*)(rec + (size_t)sv * 128 + 80);
        float v = as + ad;
        v = fmaxf(v, NEG_SLOPE * v);
        float w = __expf(v);
        w = (lane < cnt) ? w : 0.f;
        lpart += w;
        // ---- fma phase ----
        #pragma unroll
        for (int p = 0; p < 8; ++p) {
            if (p * 8 >= cnt) break;
            int lim = cnt - p * 8;
            lim = lim > 8 ? 8 : lim;
            #pragma unroll
            for (int e = 0; e < 8; ++e) {
                if (e >= lim) break;
                int j = p * 8 + e;
                int s = __shfl(sv, j);
                float wj = __shfl(w, j);
                unsigned u =
                    *(const unsigned short*)(rec + (size_t)s * 128 + cl2);
                acc = fmaf(wj, __uint_as_float(u << 16), acc);
            }
        }
    }
    #pragma unroll
    for (int off = 32; off > 0; off >>= 1) lpart += __shfl_xor(lpart, off);
    if (lane < 40) out[(size_t)node * 40 + lane] = acc / (lpart + 1e-16f);
}

// =================== final: +bias, log_softmax over 40 classes ===========

__global__ void final_k(const float* __restrict__ agg,
                        const float* __restrict__ b, float* __restrict__ out,
                        int N) {
    int n = blockIdx.x * blockDim.x + threadIdx.x;
    if (n >= N) return;
    float v[40];
    float mx = -1e30f;
    #pragma unroll
    for (int j = 0; j < 40; ++j) {
        v[j] = agg[(size_t)n * 40 + j] + b[j];
        mx = fmaxf(mx, v[j]);
    }
    float ssum = 0.f;
    #pragma unroll
    for (int j = 0; j < 40; ++j) ssum += __expf(v[j] - mx);
    float lg = __logf(ssum);
    #pragma unroll
    for (int j = 0; j < 40; ++j) out[(size_t)n * 40 + j] = v[j] - mx - lg;
}

// =================== launch ===================

extern "C" void kernel_launch(void* const* d_in, const int* in_sizes, int n_in,
                              void* d_out, int out_size, void* d_ws,
                              size_t ws_size, hipStream_t stream) {
    const float* features = (const float*)d_in[0];
    const int* edge_index = (const int*)d_in[1];
    const float* W0 = (const float*)d_in[2];
    const float* as0 = (const float*)d_in[3];
    const float* ad0 = (const float*)d_in[4];
    const float* b0 = (const float*)d_in[5];
    const float* W1 = (const float*)d_in[6];
    const float* as1 = (const float*)d_in[7];
    const float* ad1 = (const float*)d_in[8];
    const float* b1 = (const float*)d_in[9];
    const float* W2 = (const float*)d_in[10];
    const float* as2 = (const float*)d_in[11];
    const float* ad2 = (const float*)d_in[12];
    const float* b2 = (const float*)d_in[13];

    int N = in_sizes[0] / 256;
    int E = in_sizes[1] / 2;
    int Etot = E + N;
    int nbuck = (N + 255) >> 8;
    const int* srcs = edge_index;
    const int* dsts = edge_index + E;

    // workspace layout
    float* ws = (float*)d_ws;
    float* Hbuf = ws;                              // N*64 floats
    float* Abuf = Hbuf + (size_t)N * 64;           // N*64 floats
    float* adb  = Abuf + (size_t)N * 64;           // N*8
    char* recbuf = (char*)(adb + (size_t)N * 8);   // N*192 bytes
    int* row_ptr = (int*)(recbuf + (size_t)N * 192); // N+1
    int* bcnt    = row_ptr + (N + 2);              // 512
    int* bptr    = bcnt + 512;                     // 513
    int* bcur    = bptr + 513;                     // 512
    int* csr_src = bcur + 512;                     // Etot
    int2* pairs  = (int2*)Hbuf;                    // scratch, dead before gemm0

    const int B = 256;
    int gN8 = (N * 8 + B - 1) / B;
    int gN1 = (N + B - 1) / B;
    int gAg = (N + 3) / 4;
    int gBk = (Etot + EPB - 1) / EPB;
    int gGm = (N + 63) / 64;

    // ---------- CSR build ----------
    (void)hipMemsetAsync(bcnt, 0, 512 * 4, stream);
    bucket_hist_k<<<gBk, B, 0, stream>>>(dsts, bcnt, E, Etot, nbuck);
    bucket_scan_k<<<1, 512, 0, stream>>>(bcnt, bptr, bcur, nbuck, Etot);
    bucket_scatter_k<<<gBk, B, 0, stream>>>(srcs, dsts, bcur, pairs, E, Etot,
                                            nbuck);
    bucket_sort_k<<<nbuck, B, 0, stream>>>(pairs, bptr, row_ptr, csr_src, N,
                                           Etot, nbuck);

    // ---------------- layer 0 ----------------
    gemm_mfma_k<256, 64><<<gGm, B, 0, stream>>>(features, W0, Hbuf, N);
    pack8_k<<<gN8, B, 0, stream>>>(Hbuf, as0, ad0, recbuf, adb, N);
    aggr64_k<<<gAg, B, 0, stream>>>(recbuf, adb, row_ptr, csr_src, b0, Abuf,
                                    N);

    // ---------------- layer 1 ----------------
    gemm_mfma_k<64, 64><<<gGm, B, 0, stream>>>(Abuf, W1, Hbuf, N);
    pack8_k<<<gN8, B, 0, stream>>>(Hbuf, as1, ad1, recbuf, adb, N);
    aggr64_k<<<gAg, B, 0, stream>>>(recbuf, adb, row_ptr, csr_src, b1, Abuf,
                                    N);

    // ---------------- layer 2 ----------------
    gemm_mfma_k<64, 40><<<gGm, B, 0, stream>>>(Abuf, W2, Hbuf, N);
    pack40_k<<<gAg, B, 0, stream>>>(Hbuf, as2, ad2, recbuf, adb, N);
    aggr40_k<<<gAg, B, 0, stream>>>(recbuf, adb, row_ptr, csr_src, Abuf, N);
    final_k<<<gN1, B, 0, stream>>>(Abuf, b2, (float*)d_out, N);
}

// Round 10
// 710.254 us; speedup vs baseline: 1.7234x; 1.7234x over previous
//
#include <hip/hip_runtime.h>
#include <hip/hip_bf16.h>

#define NEG_SLOPE 0.2f
#define EPB 4096  // edges per block in bucket phases

typedef __attribute__((ext_vector_type(8))) short short8;
typedef __attribute__((ext_vector_type(4))) float f32x4;

__device__ __forceinline__ unsigned short f2bf(float x) {
    unsigned u = __float_as_uint(x);
    unsigned r = (u + 0x7FFFu + ((u >> 16) & 1u)) >> 16;  // RNE
    return (unsigned short)r;
}

// =================== CSR build: two-level counting sort ===================

__global__ __launch_bounds__(256) void bucket_hist_k(
    const int* __restrict__ dsts, int* __restrict__ bcnt, int E, int Etot,
    int nbuck) {
    __shared__ int lh[512];
    for (int i = threadIdx.x; i < nbuck; i += 256) lh[i] = 0;
    __syncthreads();
    int base = blockIdx.x * EPB;
    int cnt = Etot - base;
    if (cnt > EPB) cnt = EPB;
    for (int i = threadIdx.x; i < cnt; i += 256) {
        int e = base + i;
        int d = (e < E) ? dsts[e] : (e - E);
        atomicAdd(&lh[d >> 8], 1);
    }
    __syncthreads();
    for (int i = threadIdx.x; i < nbuck; i += 256) {
        int c = lh[i];
        if (c) atomicAdd(&bcnt[i], c);
    }
}

__global__ __launch_bounds__(512) void bucket_scan_k(
    const int* __restrict__ bcnt, int* __restrict__ bptr,
    int* __restrict__ bcur, int nbuck, int Etot) {
    __shared__ int tmp[512];
    int t = threadIdx.x;
    int v = (t < nbuck) ? bcnt[t] : 0;
    tmp[t] = v;
    __syncthreads();
    for (int off = 1; off < 512; off <<= 1) {
        int x = (t >= off) ? tmp[t - off] : 0;
        __syncthreads();
        tmp[t] += x;
        __syncthreads();
    }
    int excl = tmp[t] - v;
    if (t < nbuck) { bptr[t] = excl; bcur[t] = excl; }
    if (t == 0) bptr[nbuck] = Etot;
}

__global__ __launch_bounds__(256) void bucket_scatter_k(
    const int* __restrict__ srcs, const int* __restrict__ dsts,
    int* __restrict__ bcur, int2* __restrict__ pairs, int E, int Etot,
    int nbuck) {
    __shared__ int lh[512];
    __shared__ int lbase[512];
    for (int i = threadIdx.x; i < nbuck; i += 256) lh[i] = 0;
    __syncthreads();
    int base = blockIdx.x * EPB;
    int cnt = Etot - base;
    if (cnt > EPB) cnt = EPB;
    for (int i = threadIdx.x; i < cnt; i += 256) {
        int e = base + i;
        int d = (e < E) ? dsts[e] : (e - E);
        atomicAdd(&lh[d >> 8], 1);
    }
    __syncthreads();
    for (int i = threadIdx.x; i < nbuck; i += 256) {
        int c = lh[i];
        lbase[i] = c ? atomicAdd(&bcur[i], c) : 0;
    }
    __syncthreads();
    for (int i = threadIdx.x; i < nbuck; i += 256) lh[i] = 0;
    __syncthreads();
    for (int i = threadIdx.x; i < cnt; i += 256) {
        int e = base + i;
        int s, d;
        if (e < E) { s = srcs[e]; d = dsts[e]; }
        else       { s = e - E;   d = s; }
        int b = d >> 8;
        int off = atomicAdd(&lh[b], 1);
        pairs[lbase[b] + off] = make_int2(s, d);
    }
}

__global__ __launch_bounds__(256) void bucket_sort_k(
    const int2* __restrict__ pairs, const int* __restrict__ bptr,
    int* __restrict__ row_ptr, int* __restrict__ csr_src, int N, int Etot,
    int nbuck) {
    __shared__ int lh[256];
    __shared__ int lscan[256];
    int b = blockIdx.x;
    int n0 = b << 8;
    int e0 = bptr[b], e1 = bptr[b + 1];
    int t = threadIdx.x;
    lh[t] = 0;
    __syncthreads();
    for (int e = e0 + t; e < e1; e += 256)
        atomicAdd(&lh[pairs[e].y - n0], 1);
    __syncthreads();
    int v = lh[t];
    lscan[t] = v;
    __syncthreads();
    for (int off = 1; off < 256; off <<= 1) {
        int x = (t >= off) ? lscan[t - off] : 0;
        __syncthreads();
        lscan[t] += x;
        __syncthreads();
    }
    int start = e0 + lscan[t] - v;
    int n = n0 + t;
    if (n < N) row_ptr[n] = start;
    lh[t] = start;  // reuse as cursor
    __syncthreads();
    for (int e = e0 + t; e < e1; e += 256) {
        int2 p = pairs[e];
        int pos = atomicAdd(&lh[p.y - n0], 1);
        csr_src[pos] = p.x;
    }
    if (b == nbuck - 1 && t == 0) row_ptr[N] = Etot;
}

// =================== MFMA GEMM: [N,K] fp32 @ [K,COUT] fp32 -> [N,COUT] ====

template <int K, int COUT>
__global__ __launch_bounds__(256) void gemm_mfma_k(
    const float* __restrict__ x, const float* __restrict__ W,
    float* __restrict__ out, int N) {
    constexpr int NT = (COUT + 15) / 16;
    constexpr int KT = K / 32;
    __shared__ alignas(16) short Wf[KT * NT * 64 * 8];
    int tid = threadIdx.x;
    for (int f = tid; f < KT * NT * 64; f += 256) {
        int lane = f & 63;
        int ntk = f >> 6;
        int nt = ntk % NT, kt = ntk / NT;
        int q = lane >> 4, c = lane & 15;
        int n = nt * 16 + c;
        int k0 = kt * 32 + q * 8;
        short8 frag;
        #pragma unroll
        for (int j = 0; j < 8; ++j) {
            float v = (n < COUT) ? W[(size_t)(k0 + j) * COUT + n] : 0.f;
            frag[j] = (short)f2bf(v);
        }
        *(short8*)&Wf[f * 8] = frag;
    }
    __syncthreads();
    int wave = tid >> 6, lane = tid & 63;
    int q = lane >> 4, c = lane & 15;
    int m0 = blockIdx.x * 64 + wave * 16;
    int arow = m0 + c;
    int arl = arow < N ? arow : N - 1;
    f32x4 acc[NT] = {};
    for (int kt = 0; kt < KT; ++kt) {
        const float* xp = x + (size_t)arl * K + kt * 32 + q * 8;
        float4 a0 = *(const float4*)xp;
        float4 a1 = *(const float4*)(xp + 4);
        float av[8] = {a0.x, a0.y, a0.z, a0.w, a1.x, a1.y, a1.z, a1.w};
        short8 af;
        #pragma unroll
        for (int j = 0; j < 8; ++j) af[j] = (short)f2bf(av[j]);
        #pragma unroll
        for (int nt = 0; nt < NT; ++nt) {
            short8 bf = *(const short8*)&Wf[((kt * NT + nt) * 64 + lane) * 8];
            acc[nt] = __builtin_amdgcn_mfma_f32_16x16x32_bf16(af, bf, acc[nt],
                                                              0, 0, 0);
        }
    }
    int orow = m0 + q * 4;
    #pragma unroll
    for (int nt = 0; nt < NT; ++nt) {
        int n = nt * 16 + c;
        if ((COUT % 16) && n >= COUT) continue;
        #pragma unroll
        for (int reg = 0; reg < 4; ++reg) {
            int r = orow + reg;
            if (r < N) out[(size_t)r * COUT + n] = acc[nt][reg];
        }
    }
}

// ======= pack kernel, width 64: att logits + bf16 record (192 B) ==========
// rec[n]: [0..127] 64 x bf16 h ; [128..159] 8 x fp32 as

__global__ __launch_bounds__(256) void pack8_k(
    const float* __restrict__ h, const float* __restrict__ a_src,
    const float* __restrict__ a_dst, char* __restrict__ rec,
    float* __restrict__ adb, int N) {
    int idx = blockIdx.x * 256 + threadIdx.x;
    if (idx >= N * 8) return;
    int n = idx >> 3, hd = idx & 7;
    const float* hp = h + (size_t)n * 64 + hd * 8;
    float4 h0 = *(const float4*)hp;
    float4 h1 = *(const float4*)(hp + 4);
    float as = h0.x * a_src[hd * 8 + 0] + h0.y * a_src[hd * 8 + 1] +
               h0.z * a_src[hd * 8 + 2] + h0.w * a_src[hd * 8 + 3] +
               h1.x * a_src[hd * 8 + 4] + h1.y * a_src[hd * 8 + 5] +
               h1.z * a_src[hd * 8 + 6] + h1.w * a_src[hd * 8 + 7];
    float ad = h0.x * a_dst[hd * 8 + 0] + h0.y * a_dst[hd * 8 + 1] +
               h0.z * a_dst[hd * 8 + 2] + h0.w * a_dst[hd * 8 + 3] +
               h1.x * a_dst[hd * 8 + 4] + h1.y * a_dst[hd * 8 + 5] +
               h1.z * a_dst[hd * 8 + 6] + h1.w * a_dst[hd * 8 + 7];
    adb[idx] = ad;
    char* r = rec + (size_t)n * 192;
    float hv[8] = {h0.x, h0.y, h0.z, h0.w, h1.x, h1.y, h1.z, h1.w};
    unsigned short u[8];
    #pragma unroll
    for (int j = 0; j < 8; ++j) u[j] = f2bf(hv[j]);
    uint4 pk;
    pk.x = (unsigned)u[0] | ((unsigned)u[1] << 16);
    pk.y = (unsigned)u[2] | ((unsigned)u[3] << 16);
    pk.z = (unsigned)u[4] | ((unsigned)u[5] << 16);
    pk.w = (unsigned)u[6] | ((unsigned)u[7] << 16);
    *(uint4*)(r + hd * 16) = pk;
    *(float*)(r + 128 + hd * 4) = as;
}

// ======= pack kernel, width 40 (H=1): record 128 B ==========

__global__ __launch_bounds__(256) void pack40_k(
    const float* __restrict__ h, const float* __restrict__ a_src,
    const float* __restrict__ a_dst, char* __restrict__ rec,
    float* __restrict__ adb, int N) {
    int node = blockIdx.x * 4 + (threadIdx.x >> 6);
    if (node >= N) return;
    int lane = threadIdx.x & 63;
    float hv = 0.f, pas = 0.f, pad = 0.f;
    if (lane < 40) {
        hv = h[(size_t)node * 40 + lane];
        pas = hv * a_src[lane];
        pad = hv * a_dst[lane];
    }
    #pragma unroll
    for (int off = 32; off > 0; off >>= 1) {
        pas += __shfl_xor(pas, off);
        pad += __shfl_xor(pad, off);
    }
    char* r = rec + (size_t)node * 128;
    if (lane < 40)
        *(unsigned short*)(r + lane * 2) = f2bf(hv);
    if (lane == 0) {
        *(float*)(r + 80) = pas;
        adb[node] = pad;
    }
}

// ======= single-pass softmax+aggregate, width 64, packed bf16 record ======
// (round-7 version: 4x unroll, per-lane weight calc, no extra shuffles)

__global__ __launch_bounds__(256) void aggr64_k(
    const char* __restrict__ rec, const float* __restrict__ adb,
    const int* __restrict__ row_ptr, const int* __restrict__ csr_src,
    const float* __restrict__ bias, float* __restrict__ out, int N) {
    int node = blockIdx.x * 4 + (threadIdx.x >> 6);
    if (node >= N) return;
    int lane = threadIdx.x & 63;
    int hd = lane >> 3;
    int lane2 = lane * 2;
    int hoff = 128 + hd * 4;
    int beg = row_ptr[node], end = row_ptr[node + 1];
    float ad = adb[node * 8 + hd];
    float acc0 = 0.f, acc1 = 0.f, acc2 = 0.f, acc3 = 0.f;
    float l0 = 0.f, l1 = 0.f, l2 = 0.f, l3 = 0.f;
    for (int i0 = beg; i0 < end; i0 += 64) {
        int tail = end - i0;
        int sv = csr_src[i0 + (lane < tail ? lane : 0)];
        int cnt = tail < 64 ? tail : 64;
        int j = 0;
        for (; j + 4 <= cnt; j += 4) {
            int sA = __shfl(sv, j);
            int sB = __shfl(sv, j + 1);
            int sC = __shfl(sv, j + 2);
            int sD = __shfl(sv, j + 3);
            const char* rA = rec + (size_t)sA * 192;
            const char* rB = rec + (size_t)sB * 192;
            const char* rC = rec + (size_t)sC * 192;
            const char* rD = rec + (size_t)sD * 192;
            float aA = *(const float*)(rA + hoff);
            float aB = *(const float*)(rB + hoff);
            float aC = *(const float*)(rC + hoff);
            float aD = *(const float*)(rD + hoff);
            unsigned uA = *(const unsigned short*)(rA + lane2);
            unsigned uB = *(const unsigned short*)(rB + lane2);
            unsigned uC = *(const unsigned short*)(rC + lane2);
            unsigned uD = *(const unsigned short*)(rD + lane2);
            float vA = aA + ad, vB = aB + ad, vC = aC + ad, vD = aD + ad;
            vA = fmaxf(vA, NEG_SLOPE * vA);
            vB = fmaxf(vB, NEG_SLOPE * vB);
            vC = fmaxf(vC, NEG_SLOPE * vC);
            vD = fmaxf(vD, NEG_SLOPE * vD);
            float wA = __expf(vA), wB = __expf(vB);
            float wC = __expf(vC), wD = __expf(vD);
            float hA = __uint_as_float(uA << 16);
            float hB = __uint_as_float(uB << 16);
            float hC = __uint_as_float(uC << 16);
            float hD = __uint_as_float(uD << 16);
            l0 += wA; l1 += wB; l2 += wC; l3 += wD;
            acc0 = fmaf(wA, hA, acc0);
            acc1 = fmaf(wB, hB, acc1);
            acc2 = fmaf(wC, hC, acc2);
            acc3 = fmaf(wD, hD, acc3);
        }
        for (; j < cnt; ++j) {
            int sA = __shfl(sv, j);
            const char* rA = rec + (size_t)sA * 192;
            float aA = *(const float*)(rA + hoff);
            unsigned uA = *(const unsigned short*)(rA + lane2);
            float vA = aA + ad;
            vA = fmaxf(vA, NEG_SLOPE * vA);
            float wA = __expf(vA);
            l0 += wA;
            acc0 = fmaf(wA, __uint_as_float(uA << 16), acc0);
        }
    }
    float l = (l0 + l1) + (l2 + l3);
    float acc = (acc0 + acc1) + (acc2 + acc3);
    out[(size_t)node * 64 + lane] = acc / (l + 1e-16f) + bias[lane];
}

// ======= softmax+aggregate width 40 + fused bias + log_softmax ======
// round-7 style weights (per-lane, VALU-only), 4x unroll, writes d_out.

__global__ __launch_bounds__(256) void aggr40_k(
    const char* __restrict__ rec, const float* __restrict__ adb,
    const int* __restrict__ row_ptr, const int* __restrict__ csr_src,
    const float* __restrict__ bias, float* __restrict__ out, int N) {
    int node = blockIdx.x * 4 + (threadIdx.x >> 6);
    if (node >= N) return;
    int lane = threadIdx.x & 63;
    int cl2 = (lane < 40 ? lane : 0) * 2;
    int beg = row_ptr[node], end = row_ptr[node + 1];
    float ad = adb[node];
    float acc0 = 0.f, acc1 = 0.f, acc2 = 0.f, acc3 = 0.f;
    float l0 = 0.f, l1 = 0.f, l2 = 0.f, l3 = 0.f;
    for (int i0 = beg; i0 < end; i0 += 64) {
        int tail = end - i0;
        int sv = csr_src[i0 + (lane < tail ? lane : 0)];
        int cnt = tail < 64 ? tail : 64;
        int j = 0;
        for (; j + 4 <= cnt; j += 4) {
            int sA = __shfl(sv, j);
            int sB = __shfl(sv, j + 1);
            int sC = __shfl(sv, j + 2);
            int sD = __shfl(sv, j + 3);
            const char* rA = rec + (size_t)sA * 128;
            const char* rB = rec + (size_t)sB * 128;
            const char* rC = rec + (size_t)sC * 128;
            const char* rD = rec + (size_t)sD * 128;
            float aA = *(const float*)(rA + 80);
            float aB = *(const float*)(rB + 80);
            float aC = *(const float*)(rC + 80);
            float aD = *(const float*)(rD + 80);
            unsigned uA = *(const unsigned short*)(rA + cl2);
            unsigned uB = *(const unsigned short*)(rB + cl2);
            unsigned uC = *(const unsigned short*)(rC + cl2);
            unsigned uD = *(const unsigned short*)(rD + cl2);
            float vA = aA + ad, vB = aB + ad, vC = aC + ad, vD = aD + ad;
            vA = fmaxf(vA, NEG_SLOPE * vA);
            vB = fmaxf(vB, NEG_SLOPE * vB);
            vC = fmaxf(vC, NEG_SLOPE * vC);
            vD = fmaxf(vD, NEG_SLOPE * vD);
            float wA = __expf(vA), wB = __expf(vB);
            float wC = __expf(vC), wD = __expf(vD);
            l0 += wA; l1 += wB; l2 += wC; l3 += wD;
            acc0 = fmaf(wA, __uint_as_float(uA << 16), acc0);
            acc1 = fmaf(wB, __uint_as_float(uB << 16), acc1);
            acc2 = fmaf(wC, __uint_as_float(uC << 16), acc2);
            acc3 = fmaf(wD, __uint_as_float(uD << 16), acc3);
        }
        for (; j < cnt; ++j) {
            int sA = __shfl(sv, j);
            const char* rA = rec + (size_t)sA * 128;
            float aA = *(const float*)(rA + 80);
            unsigned uA = *(const unsigned short*)(rA + cl2);
            float vA = aA + ad;
            vA = fmaxf(vA, NEG_SLOPE * vA);
            float wA = __expf(vA);
            l0 += wA;
            acc0 = fmaf(wA, __uint_as_float(uA << 16), acc0);
        }
    }
    float l = (l0 + l1) + (l2 + l3);
    float acc = (acc0 + acc1) + (acc2 + acc3);
    // fused bias + log_softmax over the 40 class lanes
    float val = acc / (l + 1e-16f) + ((lane < 40) ? bias[lane] : 0.f);
    float mval = (lane < 40) ? val : -1e30f;
    #pragma unroll
    for (int off = 32; off > 0; off >>= 1)
        mval = fmaxf(mval, __shfl_xor(mval, off));
    float ex = (lane < 40) ? __expf(val - mval) : 0.f;
    #pragma unroll
    for (int off = 32; off > 0; off >>= 1) ex += __shfl_xor(ex, off);
    if (lane < 40)
        out[(size_t)node * 40 + lane] = val - mval - __logf(ex);
}

// =================== launch ===================

extern "C" void kernel_launch(void* const* d_in, const int* in_sizes, int n_in,
                              void* d_out, int out_size, void* d_ws,
                              size_t ws_size, hipStream_t stream) {
    const float* features = (const float*)d_in[0];
    const int* edge_index = (const int*)d_in[1];
    const float* W0 = (const float*)d_in[2];
    const float* as0 = (const float*)d_in[3];
    const float* ad0 = (const float*)d_in[4];
    const float* b0 = (const float*)d_in[5];
    const float* W1 = (const float*)d_in[6];
    const float* as1 = (const float*)d_in[7];
    const float* ad1 = (const float*)d_in[8];
    const float* b1 = (const float*)d_in[9];
    const float* W2 = (const float*)d_in[10];
    const float* as2 = (const float*)d_in[11];
    const float* ad2 = (const float*)d_in[12];
    const float* b2 = (const float*)d_in[13];

    int N = in_sizes[0] / 256;
    int E = in_sizes[1] / 2;
    int Etot = E + N;
    int nbuck = (N + 255) >> 8;
    const int* srcs = edge_index;
    const int* dsts = edge_index + E;

    // workspace layout
    float* ws = (float*)d_ws;
    float* Hbuf = ws;                              // N*64 floats
    float* Abuf = Hbuf + (size_t)N * 64;           // N*64 floats
    float* adb  = Abuf + (size_t)N * 64;           // N*8
    char* recbuf = (char*)(adb + (size_t)N * 8);   // N*192 bytes
    int* row_ptr = (int*)(recbuf + (size_t)N * 192); // N+1
    int* bcnt    = row_ptr + (N + 2);              // 512
    int* bptr    = bcnt + 512;                     // 513
    int* bcur    = bptr + 513;                     // 512
    int* csr_src = bcur + 512;                     // Etot
    int2* pairs  = (int2*)Hbuf;                    // scratch, dead before gemm0

    const int B = 256;
    int gN8 = (N * 8 + B - 1) / B;
    int gAg = (N + 3) / 4;
    int gBk = (Etot + EPB - 1) / EPB;
    int gGm = (N + 63) / 64;

    // ---------- CSR build ----------
    (void)hipMemsetAsync(bcnt, 0, 512 * 4, stream);
    bucket_hist_k<<<gBk, B, 0, stream>>>(dsts, bcnt, E, Etot, nbuck);
    bucket_scan_k<<<1, 512, 0, stream>>>(bcnt, bptr, bcur, nbuck, Etot);
    bucket_scatter_k<<<gBk, B, 0, stream>>>(srcs, dsts, bcur, pairs, E, Etot,
                                            nbuck);
    bucket_sort_k<<<nbuck, B, 0, stream>>>(pairs, bptr, row_ptr, csr_src, N,
                                           Etot, nbuck);

    // ---------------- layer 0 ----------------
    gemm_mfma_k<256, 64><<<gGm, B, 0, stream>>>(features, W0, Hbuf, N);
    pack8_k<<<gN8, B, 0, stream>>>(Hbuf, as0, ad0, recbuf, adb, N);
    aggr64_k<<<gAg, B, 0, stream>>>(recbuf, adb, row_ptr, csr_src, b0, Abuf,
                                    N);

    // ---------------- layer 1 ----------------
    gemm_mfma_k<64, 64><<<gGm, B, 0, stream>>>(Abuf, W1, Hbuf, N);
    pack8_k<<<gN8, B, 0, stream>>>(Hbuf, as1, ad1, recbuf, adb, N);
    aggr64_k<<<gAg, B, 0, stream>>>(recbuf, adb, row_ptr, csr_src, b1, Abuf,
                                    N);

    // ---------------- layer 2 ----------------
    gemm_mfma_k<64, 40><<<gGm, B, 0, stream>>>(Abuf, W2, Hbuf, N);
    pack40_k<<<gAg, B, 0, stream>>>(Hbuf, as2, ad2, recbuf, adb, N);
    aggr40_k<<<gAg, B, 0, stream>>>(recbuf, adb, row_ptr, csr_src, b2,
                                    (float*)d_out, N);
}

// Round 12
// 706.760 us; speedup vs baseline: 1.7319x; 1.0049x over previous
//
#include <hip/hip_runtime.h>
#include <hip/hip_bf16.h>

#define NEG_SLOPE 0.2f
#define LOG2E 1.44269504f
#define EPB 4096  // edges per block in bucket phases

typedef __attribute__((ext_vector_type(8))) short short8;
typedef __attribute__((ext_vector_type(4))) float f32x4;

__device__ __forceinline__ unsigned short f2bf(float x) {
    unsigned u = __float_as_uint(x);
    unsigned r = (u + 0x7FFFu + ((u >> 16) & 1u)) >> 16;  // RNE
    return (unsigned short)r;
}

__device__ __forceinline__ float fexp2(float x) {
    return __builtin_amdgcn_exp2f(x);  // v_exp_f32: 2^x
}

// =================== CSR build: two-level counting sort ===================

__global__ __launch_bounds__(256) void bucket_hist_k(
    const int* __restrict__ dsts, int* __restrict__ bcnt, int E, int Etot,
    int nbuck) {
    __shared__ int lh[512];
    for (int i = threadIdx.x; i < nbuck; i += 256) lh[i] = 0;
    __syncthreads();
    int base = blockIdx.x * EPB;
    int cnt = Etot - base;
    if (cnt > EPB) cnt = EPB;
    for (int i = threadIdx.x; i < cnt; i += 256) {
        int e = base + i;
        int d = (e < E) ? dsts[e] : (e - E);
        atomicAdd(&lh[d >> 8], 1);
    }
    __syncthreads();
    for (int i = threadIdx.x; i < nbuck; i += 256) {
        int c = lh[i];
        if (c) atomicAdd(&bcnt[i], c);
    }
}

__global__ __launch_bounds__(512) void bucket_scan_k(
    const int* __restrict__ bcnt, int* __restrict__ bptr,
    int* __restrict__ bcur, int nbuck, int Etot) {
    __shared__ int tmp[512];
    int t = threadIdx.x;
    int v = (t < nbuck) ? bcnt[t] : 0;
    tmp[t] = v;
    __syncthreads();
    for (int off = 1; off < 512; off <<= 1) {
        int x = (t >= off) ? tmp[t - off] : 0;
        __syncthreads();
        tmp[t] += x;
        __syncthreads();
    }
    int excl = tmp[t] - v;
    if (t < nbuck) { bptr[t] = excl; bcur[t] = excl; }
    if (t == 0) bptr[nbuck] = Etot;
}

__global__ __launch_bounds__(256) void bucket_scatter_k(
    const int* __restrict__ srcs, const int* __restrict__ dsts,
    int* __restrict__ bcur, int2* __restrict__ pairs, int E, int Etot,
    int nbuck) {
    __shared__ int lh[512];
    __shared__ int lbase[512];
    for (int i = threadIdx.x; i < nbuck; i += 256) lh[i] = 0;
    __syncthreads();
    int base = blockIdx.x * EPB;
    int cnt = Etot - base;
    if (cnt > EPB) cnt = EPB;
    for (int i = threadIdx.x; i < cnt; i += 256) {
        int e = base + i;
        int d = (e < E) ? dsts[e] : (e - E);
        atomicAdd(&lh[d >> 8], 1);
    }
    __syncthreads();
    for (int i = threadIdx.x; i < nbuck; i += 256) {
        int c = lh[i];
        lbase[i] = c ? atomicAdd(&bcur[i], c) : 0;
    }
    __syncthreads();
    for (int i = threadIdx.x; i < nbuck; i += 256) lh[i] = 0;
    __syncthreads();
    for (int i = threadIdx.x; i < cnt; i += 256) {
        int e = base + i;
        int s, d;
        if (e < E) { s = srcs[e]; d = dsts[e]; }
        else       { s = e - E;   d = s; }
        int b = d >> 8;
        int off = atomicAdd(&lh[b], 1);
        pairs[lbase[b] + off] = make_int2(s, d);
    }
}

__global__ __launch_bounds__(256) void bucket_sort_k(
    const int2* __restrict__ pairs, const int* __restrict__ bptr,
    int* __restrict__ row_ptr, int* __restrict__ csr_src, int N, int Etot,
    int nbuck) {
    __shared__ int lh[256];
    __shared__ int lscan[256];
    int b = blockIdx.x;
    int n0 = b << 8;
    int e0 = bptr[b], e1 = bptr[b + 1];
    int t = threadIdx.x;
    lh[t] = 0;
    __syncthreads();
    for (int e = e0 + t; e < e1; e += 256)
        atomicAdd(&lh[pairs[e].y - n0], 1);
    __syncthreads();
    int v = lh[t];
    lscan[t] = v;
    __syncthreads();
    for (int off = 1; off < 256; off <<= 1) {
        int x = (t >= off) ? lscan[t - off] : 0;
        __syncthreads();
        lscan[t] += x;
        __syncthreads();
    }
    int start = e0 + lscan[t] - v;
    int n = n0 + t;
    if (n < N) row_ptr[n] = start;
    lh[t] = start;  // reuse as cursor
    __syncthreads();
    for (int e = e0 + t; e < e1; e += 256) {
        int2 p = pairs[e];
        int pos = atomicAdd(&lh[p.y - n0], 1);
        csr_src[pos] = p.x;
    }
    if (b == nbuck - 1 && t == 0) row_ptr[N] = Etot;
}

// =================== MFMA GEMM: [N,K] fp32 @ [K,COUT] fp32 -> [N,COUT] ====

template <int K, int COUT>
__global__ __launch_bounds__(256) void gemm_mfma_k(
    const float* __restrict__ x, const float* __restrict__ W,
    float* __restrict__ out, int N) {
    constexpr int NT = (COUT + 15) / 16;
    constexpr int KT = K / 32;
    __shared__ alignas(16) short Wf[KT * NT * 64 * 8];
    int tid = threadIdx.x;
    for (int f = tid; f < KT * NT * 64; f += 256) {
        int lane = f & 63;
        int ntk = f >> 6;
        int nt = ntk % NT, kt = ntk / NT;
        int q = lane >> 4, c = lane & 15;
        int n = nt * 16 + c;
        int k0 = kt * 32 + q * 8;
        short8 frag;
        #pragma unroll
        for (int j = 0; j < 8; ++j) {
            float v = (n < COUT) ? W[(size_t)(k0 + j) * COUT + n] : 0.f;
            frag[j] = (short)f2bf(v);
        }
        *(short8*)&Wf[f * 8] = frag;
    }
    __syncthreads();
    int wave = tid >> 6, lane = tid & 63;
    int q = lane >> 4, c = lane & 15;
    int m0 = blockIdx.x * 64 + wave * 16;
    int arow = m0 + c;
    int arl = arow < N ? arow : N - 1;
    f32x4 acc[NT] = {};
    for (int kt = 0; kt < KT; ++kt) {
        const float* xp = x + (size_t)arl * K + kt * 32 + q * 8;
        float4 a0 = *(const float4*)xp;
        float4 a1 = *(const float4*)(xp + 4);
        float av[8] = {a0.x, a0.y, a0.z, a0.w, a1.x, a1.y, a1.z, a1.w};
        short8 af;
        #pragma unroll
        for (int j = 0; j < 8; ++j) af[j] = (short)f2bf(av[j]);
        #pragma unroll
        for (int nt = 0; nt < NT; ++nt) {
            short8 bf = *(const short8*)&Wf[((kt * NT + nt) * 64 + lane) * 8];
            acc[nt] = __builtin_amdgcn_mfma_f32_16x16x32_bf16(af, bf, acc[nt],
                                                              0, 0, 0);
        }
    }
    int orow = m0 + q * 4;
    #pragma unroll
    for (int nt = 0; nt < NT; ++nt) {
        int n = nt * 16 + c;
        if ((COUT % 16) && n >= COUT) continue;
        #pragma unroll
        for (int reg = 0; reg < 4; ++reg) {
            int r = orow + reg;
            if (r < N) out[(size_t)r * COUT + n] = acc[nt][reg];
        }
    }
}

// ======= pack kernel, width 64: att logits + bf16 record (192 B) ==========
// rec[n]: [0..127] 64 x bf16 h ; [128..159] 8 x fp32 as*log2e
// adb holds ad*log2e (leaky-relu is positively homogeneous, so
// pre-scaling by log2e commutes with it; weights use exp2 directly).

__global__ __launch_bounds__(256) void pack8_k(
    const float* __restrict__ h, const float* __restrict__ a_src,
    const float* __restrict__ a_dst, char* __restrict__ rec,
    float* __restrict__ adb, int N) {
    int idx = blockIdx.x * 256 + threadIdx.x;
    if (idx >= N * 8) return;
    int n = idx >> 3, hd = idx & 7;
    const float* hp = h + (size_t)n * 64 + hd * 8;
    float4 h0 = *(const float4*)hp;
    float4 h1 = *(const float4*)(hp + 4);
    float as = h0.x * a_src[hd * 8 + 0] + h0.y * a_src[hd * 8 + 1] +
               h0.z * a_src[hd * 8 + 2] + h0.w * a_src[hd * 8 + 3] +
               h1.x * a_src[hd * 8 + 4] + h1.y * a_src[hd * 8 + 5] +
               h1.z * a_src[hd * 8 + 6] + h1.w * a_src[hd * 8 + 7];
    float ad = h0.x * a_dst[hd * 8 + 0] + h0.y * a_dst[hd * 8 + 1] +
               h0.z * a_dst[hd * 8 + 2] + h0.w * a_dst[hd * 8 + 3] +
               h1.x * a_dst[hd * 8 + 4] + h1.y * a_dst[hd * 8 + 5] +
               h1.z * a_dst[hd * 8 + 6] + h1.w * a_dst[hd * 8 + 7];
    adb[idx] = ad * LOG2E;
    char* r = rec + (size_t)n * 192;
    float hv[8] = {h0.x, h0.y, h0.z, h0.w, h1.x, h1.y, h1.z, h1.w};
    unsigned short u[8];
    #pragma unroll
    for (int j = 0; j < 8; ++j) u[j] = f2bf(hv[j]);
    uint4 pk;
    pk.x = (unsigned)u[0] | ((unsigned)u[1] << 16);
    pk.y = (unsigned)u[2] | ((unsigned)u[3] << 16);
    pk.z = (unsigned)u[4] | ((unsigned)u[5] << 16);
    pk.w = (unsigned)u[6] | ((unsigned)u[7] << 16);
    *(uint4*)(r + hd * 16) = pk;
    *(float*)(r + 128 + hd * 4) = as * LOG2E;
}

// ======= pack kernel, width 40 (H=1): record 128 B ==========

__global__ __launch_bounds__(256) void pack40_k(
    const float* __restrict__ h, const float* __restrict__ a_src,
    const float* __restrict__ a_dst, char* __restrict__ rec,
    float* __restrict__ adb, int N) {
    int node = blockIdx.x * 4 + (threadIdx.x >> 6);
    if (node >= N) return;
    int lane = threadIdx.x & 63;
    float hv = 0.f, pas = 0.f, pad = 0.f;
    if (lane < 40) {
        hv = h[(size_t)node * 40 + lane];
        pas = hv * a_src[lane];
        pad = hv * a_dst[lane];
    }
    #pragma unroll
    for (int off = 32; off > 0; off >>= 1) {
        pas += __shfl_xor(pas, off);
        pad += __shfl_xor(pad, off);
    }
    char* r = rec + (size_t)node * 128;
    if (lane < 40)
        *(unsigned short*)(r + lane * 2) = f2bf(hv);
    if (lane == 0) {
        *(float*)(r + 80) = pas * LOG2E;
        adb[node] = pad * LOG2E;
    }
}

// ======= single-pass softmax+aggregate, width 64, packed bf16 record ======
// readlane -> scalar src index -> SALU addressing (saddr-form loads)

__global__ __launch_bounds__(256) void aggr64_k(
    const char* __restrict__ rec, const float* __restrict__ adb,
    const int* __restrict__ row_ptr, const int* __restrict__ csr_src,
    const float* __restrict__ bias, float* __restrict__ out, int N) {
    int node = blockIdx.x * 4 + (threadIdx.x >> 6);
    if (node >= N) return;
    int lane = threadIdx.x & 63;
    int hd = lane >> 3;
    int lane2 = lane * 2;
    int hoff = 128 + hd * 4;
    int beg = row_ptr[node], end = row_ptr[node + 1];
    float ad = adb[node * 8 + hd];
    float acc0 = 0.f, acc1 = 0.f, acc2 = 0.f, acc3 = 0.f;
    float l0 = 0.f, l1 = 0.f, l2 = 0.f, l3 = 0.f;
    for (int i0 = beg; i0 < end; i0 += 64) {
        int tail = end - i0;
        int sv = csr_src[i0 + (lane < tail ? lane : 0)];
        int cnt = tail < 64 ? tail : 64;
        int j = 0;
        for (; j + 4 <= cnt; j += 4) {
            int sA = __builtin_amdgcn_readlane(sv, j);
            int sB = __builtin_amdgcn_readlane(sv, j + 1);
            int sC = __builtin_amdgcn_readlane(sv, j + 2);
            int sD = __builtin_amdgcn_readlane(sv, j + 3);
            const char* rA = rec + (size_t)sA * 192;
            const char* rB = rec + (size_t)sB * 192;
            const char* rC = rec + (size_t)sC * 192;
            const char* rD = rec + (size_t)sD * 192;
            float aA = *(const float*)(rA + hoff);
            float aB = *(const float*)(rB + hoff);
            float aC = *(const float*)(rC + hoff);
            float aD = *(const float*)(rD + hoff);
            unsigned uA = *(const unsigned short*)(rA + lane2);
            unsigned uB = *(const unsigned short*)(rB + lane2);
            unsigned uC = *(const unsigned short*)(rC + lane2);
            unsigned uD = *(const unsigned short*)(rD + lane2);
            float vA = aA + ad, vB = aB + ad, vC = aC + ad, vD = aD + ad;
            vA = fmaxf(vA, NEG_SLOPE * vA);
            vB = fmaxf(vB, NEG_SLOPE * vB);
            vC = fmaxf(vC, NEG_SLOPE * vC);
            vD = fmaxf(vD, NEG_SLOPE * vD);
            float wA = fexp2(vA), wB = fexp2(vB);
            float wC = fexp2(vC), wD = fexp2(vD);
            float hA = __uint_as_float(uA << 16);
            float hB = __uint_as_float(uB << 16);
            float hC = __uint_as_float(uC << 16);
            float hD = __uint_as_float(uD << 16);
            l0 += wA; l1 += wB; l2 += wC; l3 += wD;
            acc0 = fmaf(wA, hA, acc0);
            acc1 = fmaf(wB, hB, acc1);
            acc2 = fmaf(wC, hC, acc2);
            acc3 = fmaf(wD, hD, acc3);
        }
        for (; j < cnt; ++j) {
            int sA = __builtin_amdgcn_readlane(sv, j);
            const char* rA = rec + (size_t)sA * 192;
            float aA = *(const float*)(rA + hoff);
            unsigned uA = *(const unsigned short*)(rA + lane2);
            float vA = aA + ad;
            vA = fmaxf(vA, NEG_SLOPE * vA);
            float wA = fexp2(vA);
            l0 += wA;
            acc0 = fmaf(wA, __uint_as_float(uA << 16), acc0);
        }
    }
    float l = (l0 + l1) + (l2 + l3);
    float acc = (acc0 + acc1) + (acc2 + acc3);
    out[(size_t)node * 64 + lane] = acc / (l + 1e-16f) + bias[lane];
}

// ======= softmax+aggregate width 40 + fused bias + log_softmax ======

__global__ __launch_bounds__(256) void aggr40_k(
    const char* __restrict__ rec, const float* __restrict__ adb,
    const int* __restrict__ row_ptr, const int* __restrict__ csr_src,
    const float* __restrict__ bias, float* __restrict__ out, int N) {
    int node = blockIdx.x * 4 + (threadIdx.x >> 6);
    if (node >= N) return;
    int lane = threadIdx.x & 63;
    int cl2 = (lane < 40 ? lane : 0) * 2;
    int beg = row_ptr[node], end = row_ptr[node + 1];
    float ad = adb[node];
    float acc0 = 0.f, acc1 = 0.f, acc2 = 0.f, acc3 = 0.f;
    float l0 = 0.f, l1 = 0.f, l2 = 0.f, l3 = 0.f;
    for (int i0 = beg; i0 < end; i0 += 64) {
        int tail = end - i0;
        int sv = csr_src[i0 + (lane < tail ? lane : 0)];
        int cnt = tail < 64 ? tail : 64;
        int j = 0;
        for (; j + 4 <= cnt; j += 4) {
            int sA = __builtin_amdgcn_readlane(sv, j);
            int sB = __builtin_amdgcn_readlane(sv, j + 1);
            int sC = __builtin_amdgcn_readlane(sv, j + 2);
            int sD = __builtin_amdgcn_readlane(sv, j + 3);
            const char* rA = rec + (size_t)sA * 128;
            const char* rB = rec + (size_t)sB * 128;
            const char* rC = rec + (size_t)sC * 128;
            const char* rD = rec + (size_t)sD * 128;
            float aA = *(const float*)(rA + 80);
            float aB = *(const float*)(rB + 80);
            float aC = *(const float*)(rC + 80);
            float aD = *(const float*)(rD + 80);
            unsigned uA = *(const unsigned short*)(rA + cl2);
            unsigned uB = *(const unsigned short*)(rB + cl2);
            unsigned uC = *(const unsigned short*)(rC + cl2);
            unsigned uD = *(const unsigned short*)(rD + cl2);
            float vA = aA + ad, vB = aB + ad, vC = aC + ad, vD = aD + ad;
            vA = fmaxf(vA, NEG_SLOPE * vA);
            vB = fmaxf(vB, NEG_SLOPE * vB);
            vC = fmaxf(vC, NEG_SLOPE * vC);
            vD = fmaxf(vD, NEG_SLOPE * vD);
            float wA = fexp2(vA), wB = fexp2(vB);
            float wC = fexp2(vC), wD = fexp2(vD);
            l0 += wA; l1 += wB; l2 += wC; l3 += wD;
            acc0 = fmaf(wA, __uint_as_float(uA << 16), acc0);
            acc1 = fmaf(wB, __uint_as_float(uB << 16), acc1);
            acc2 = fmaf(wC, __uint_as_float(uC << 16), acc2);
            acc3 = fmaf(wD, __uint_as_float(uD << 16), acc3);
        }
        for (; j < cnt; ++j) {
            int sA = __builtin_amdgcn_readlane(sv, j);
            const char* rA = rec + (size_t)sA * 128;
            float aA = *(const float*)(rA + 80);
            unsigned uA = *(const unsigned short*)(rA + cl2);
            float vA = aA + ad;
            vA = fmaxf(vA, NEG_SLOPE * vA);
            float wA = fexp2(vA);
            l0 += wA;
            acc0 = fmaf(wA, __uint_as_float(uA << 16), acc0);
        }
    }
    float l = (l0 + l1) + (l2 + l3);
    float acc = (acc0 + acc1) + (acc2 + acc3);
    // fused bias + log_softmax over the 40 class lanes
    float val = acc / (l + 1e-16f) + ((lane < 40) ? bias[lane] : 0.f);
    float mval = (lane < 40) ? val : -1e30f;
    #pragma unroll
    for (int off = 32; off > 0; off >>= 1)
        mval = fmaxf(mval, __shfl_xor(mval, off));
    float ex = (lane < 40) ? __expf(val - mval) : 0.f;
    #pragma unroll
    for (int off = 32; off > 0; off >>= 1) ex += __shfl_xor(ex, off);
    if (lane < 40)
        out[(size_t)node * 40 + lane] = val - mval - __logf(ex);
}

// =================== launch ===================

extern "C" void kernel_launch(void* const* d_in, const int* in_sizes, int n_in,
                              void* d_out, int out_size, void* d_ws,
                              size_t ws_size, hipStream_t stream) {
    const float* features = (const float*)d_in[0];
    const int* edge_index = (const int*)d_in[1];
    const float* W0 = (const float*)d_in[2];
    const float* as0 = (const float*)d_in[3];
    const float* ad0 = (const float*)d_in[4];
    const float* b0 = (const float*)d_in[5];
    const float* W1 = (const float*)d_in[6];
    const float* as1 = (const float*)d_in[7];
    const float* ad1 = (const float*)d_in[8];
    const float* b1 = (const float*)d_in[9];
    const float* W2 = (const float*)d_in[10];
    const float* as2 = (const float*)d_in[11];
    const float* ad2 = (const float*)d_in[12];
    const float* b2 = (const float*)d_in[13];

    int N = in_sizes[0] / 256;
    int E = in_sizes[1] / 2;
    int Etot = E + N;
    int nbuck = (N + 255) >> 8;
    const int* srcs = edge_index;
    const int* dsts = edge_index + E;

    // workspace layout
    float* ws = (float*)d_ws;
    float* Hbuf = ws;                              // N*64 floats
    float* Abuf = Hbuf + (size_t)N * 64;           // N*64 floats
    float* adb  = Abuf + (size_t)N * 64;           // N*8
    char* recbuf = (char*)(adb + (size_t)N * 8);   // N*192 bytes
    int* row_ptr = (int*)(recbuf + (size_t)N * 192); // N+1
    int* bcnt    = row_ptr + (N + 2);              // 512
    int* bptr    = bcnt + 512;                     // 513
    int* bcur    = bptr + 513;                     // 512
    int* csr_src = bcur + 512;                     // Etot
    int2* pairs  = (int2*)Hbuf;                    // scratch, dead before gemm0

    const int B = 256;
    int gN8 = (N * 8 + B - 1) / B;
    int gAg = (N + 3) / 4;
    int gBk = (Etot + EPB - 1) / EPB;
    int gGm = (N + 63) / 64;

    // ---------- CSR build ----------
    (void)hipMemsetAsync(bcnt, 0, 512 * 4, stream);
    bucket_hist_k<<<gBk, B, 0, stream>>>(dsts, bcnt, E, Etot, nbuck);
    bucket_scan_k<<<1, 512, 0, stream>>>(bcnt, bptr, bcur, nbuck, Etot);
    bucket_scatter_k<<<gBk, B, 0, stream>>>(srcs, dsts, bcur, pairs, E, Etot,
                                            nbuck);
    bucket_sort_k<<<nbuck, B, 0, stream>>>(pairs, bptr, row_ptr, csr_src, N,
                                           Etot, nbuck);

    // ---------------- layer 0 ----------------
    gemm_mfma_k<256, 64><<<gGm, B, 0, stream>>>(features, W0, Hbuf, N);
    pack8_k<<<gN8, B, 0, stream>>>(Hbuf, as0, ad0, recbuf, adb, N);
    aggr64_k<<<gAg, B, 0, stream>>>(recbuf, adb, row_ptr, csr_src, b0, Abuf,
                                    N);

    // ---------------- layer 1 ----------------
    gemm_mfma_k<64, 64><<<gGm, B, 0, stream>>>(Abuf, W1, Hbuf, N);
    pack8_k<<<gN8, B, 0, stream>>>(Hbuf, as1, ad1, recbuf, adb, N);
    aggr64_k<<<gAg, B, 0, stream>>>(recbuf, adb, row_ptr, csr_src, b1, Abuf,
                                    N);

    // ---------------- layer 2 ----------------
    gemm_mfma_k<64, 40><<<gGm, B, 0, stream>>>(Abuf, W2, Hbuf, N);
    pack40_k<<<gAg, B, 0, stream>>>(Hbuf, as2, ad2, recbuf, adb, N);
    aggr40_k<<<gAg, B, 0, stream>>>(recbuf, adb, row_ptr, csr_src, b2,
                                    (float*)d_out, N);
}

// Round 13
// 680.599 us; speedup vs baseline: 1.7984x; 1.0384x over previous
//
#include <hip/hip_runtime.h>
#include <hip/hip_bf16.h>

#define NEG_SLOPE 0.2f
#define LOG2E 1.44269504f
#define EPB 4096  // edges per block in bucket phases

typedef __attribute__((ext_vector_type(8))) short short8;
typedef __attribute__((ext_vector_type(4))) float f32x4;

__device__ __forceinline__ unsigned short f2bf(float x) {
    unsigned u = __float_as_uint(x);
    unsigned r = (u + 0x7FFFu + ((u >> 16) & 1u)) >> 16;  // RNE
    return (unsigned short)r;
}

__device__ __forceinline__ float fexp2(float x) {
    return __builtin_amdgcn_exp2f(x);  // v_exp_f32: 2^x
}

// =================== CSR build: two-level counting sort ===================

__global__ __launch_bounds__(256) void bucket_hist_k(
    const int* __restrict__ dsts, int* __restrict__ bcnt, int E, int Etot,
    int nbuck) {
    __shared__ int lh[512];
    for (int i = threadIdx.x; i < nbuck; i += 256) lh[i] = 0;
    __syncthreads();
    int base = blockIdx.x * EPB;
    int cnt = Etot - base;
    if (cnt > EPB) cnt = EPB;
    for (int i = threadIdx.x; i < cnt; i += 256) {
        int e = base + i;
        int d = (e < E) ? dsts[e] : (e - E);
        atomicAdd(&lh[d >> 8], 1);
    }
    __syncthreads();
    for (int i = threadIdx.x; i < nbuck; i += 256) {
        int c = lh[i];
        if (c) atomicAdd(&bcnt[i], c);
    }
}

__global__ __launch_bounds__(512) void bucket_scan_k(
    const int* __restrict__ bcnt, int* __restrict__ bptr,
    int* __restrict__ bcur, int nbuck, int Etot) {
    __shared__ int tmp[512];
    int t = threadIdx.x;
    int v = (t < nbuck) ? bcnt[t] : 0;
    tmp[t] = v;
    __syncthreads();
    for (int off = 1; off < 512; off <<= 1) {
        int x = (t >= off) ? tmp[t - off] : 0;
        __syncthreads();
        tmp[t] += x;
        __syncthreads();
    }
    int excl = tmp[t] - v;
    if (t < nbuck) { bptr[t] = excl; bcur[t] = excl; }
    if (t == 0) bptr[nbuck] = Etot;
}

__global__ __launch_bounds__(256) void bucket_scatter_k(
    const int* __restrict__ srcs, const int* __restrict__ dsts,
    int* __restrict__ bcur, int2* __restrict__ pairs, int E, int Etot,
    int nbuck) {
    __shared__ int lh[512];
    __shared__ int lbase[512];
    for (int i = threadIdx.x; i < nbuck; i += 256) lh[i] = 0;
    __syncthreads();
    int base = blockIdx.x * EPB;
    int cnt = Etot - base;
    if (cnt > EPB) cnt = EPB;
    for (int i = threadIdx.x; i < cnt; i += 256) {
        int e = base + i;
        int d = (e < E) ? dsts[e] : (e - E);
        atomicAdd(&lh[d >> 8], 1);
    }
    __syncthreads();
    for (int i = threadIdx.x; i < nbuck; i += 256) {
        int c = lh[i];
        lbase[i] = c ? atomicAdd(&bcur[i], c) : 0;
    }
    __syncthreads();
    for (int i = threadIdx.x; i < nbuck; i += 256) lh[i] = 0;
    __syncthreads();
    for (int i = threadIdx.x; i < cnt; i += 256) {
        int e = base + i;
        int s, d;
        if (e < E) { s = srcs[e]; d = dsts[e]; }
        else       { s = e - E;   d = s; }
        int b = d >> 8;
        int off = atomicAdd(&lh[b], 1);
        pairs[lbase[b] + off] = make_int2(s, d);
    }
}

__global__ __launch_bounds__(256) void bucket_sort_k(
    const int2* __restrict__ pairs, const int* __restrict__ bptr,
    int* __restrict__ row_ptr, int* __restrict__ csr_src, int N, int Etot,
    int nbuck) {
    __shared__ int lh[256];
    __shared__ int lscan[256];
    int b = blockIdx.x;
    int n0 = b << 8;
    int e0 = bptr[b], e1 = bptr[b + 1];
    int t = threadIdx.x;
    lh[t] = 0;
    __syncthreads();
    for (int e = e0 + t; e < e1; e += 256)
        atomicAdd(&lh[pairs[e].y - n0], 1);
    __syncthreads();
    int v = lh[t];
    lscan[t] = v;
    __syncthreads();
    for (int off = 1; off < 256; off <<= 1) {
        int x = (t >= off) ? lscan[t - off] : 0;
        __syncthreads();
        lscan[t] += x;
        __syncthreads();
    }
    int start = e0 + lscan[t] - v;
    int n = n0 + t;
    if (n < N) row_ptr[n] = start;
    lh[t] = start;  // reuse as cursor
    __syncthreads();
    for (int e = e0 + t; e < e1; e += 256) {
        int2 p = pairs[e];
        int pos = atomicAdd(&lh[p.y - n0], 1);
        csr_src[pos] = p.x;
    }
    if (b == nbuck - 1 && t == 0) row_ptr[N] = Etot;
}

// ====== fused MFMA GEMM + pack8 (COUT=64): x[N,K] @ W[K,64] -> records =====
// main loop identical to gemm_mfma_k; epilogue stages acc in LDS (aliased
// over the dead W-fragment buffer) then packs bf16 record + as/ad logits.

template <int K>
__global__ __launch_bounds__(256) void gemm_pack8_k(
    const float* __restrict__ x, const float* __restrict__ W,
    const float* __restrict__ a_src, const float* __restrict__ a_dst,
    char* __restrict__ rec, float* __restrict__ adb, int N) {
    constexpr int NT = 4;
    constexpr int KT = K / 32;
    constexpr size_t WF_BYTES = (size_t)KT * NT * 64 * 8 * sizeof(short);
    constexpr size_t H_BYTES = (size_t)64 * 65 * sizeof(float);
    __shared__ alignas(16) char smem[WF_BYTES > H_BYTES ? WF_BYTES : H_BYTES];
    short* Wf = (short*)smem;
    float* hL = (float*)smem;
    int tid = threadIdx.x;
    for (int f = tid; f < KT * NT * 64; f += 256) {
        int lane = f & 63;
        int ntk = f >> 6;
        int nt = ntk % NT, kt = ntk / NT;
        int q = lane >> 4, c = lane & 15;
        int n = nt * 16 + c;
        int k0 = kt * 32 + q * 8;
        short8 frag;
        #pragma unroll
        for (int j = 0; j < 8; ++j)
            frag[j] = (short)f2bf(W[(size_t)(k0 + j) * 64 + n]);
        *(short8*)&Wf[f * 8] = frag;
    }
    __syncthreads();
    int wave = tid >> 6, lane = tid & 63;
    int q = lane >> 4, c = lane & 15;
    int m0 = blockIdx.x * 64 + wave * 16;
    int arow = m0 + c;
    int arl = arow < N ? arow : N - 1;
    f32x4 acc[NT] = {};
    for (int kt = 0; kt < KT; ++kt) {
        const float* xp = x + (size_t)arl * K + kt * 32 + q * 8;
        float4 a0 = *(const float4*)xp;
        float4 a1 = *(const float4*)(xp + 4);
        float av[8] = {a0.x, a0.y, a0.z, a0.w, a1.x, a1.y, a1.z, a1.w};
        short8 af;
        #pragma unroll
        for (int j = 0; j < 8; ++j) af[j] = (short)f2bf(av[j]);
        #pragma unroll
        for (int nt = 0; nt < NT; ++nt) {
            short8 bf = *(const short8*)&Wf[((kt * NT + nt) * 64 + lane) * 8];
            acc[nt] = __builtin_amdgcn_mfma_f32_16x16x32_bf16(af, bf, acc[nt],
                                                              0, 0, 0);
        }
    }
    __syncthreads();  // all waves done reading Wf; reuse as hL
    int lrow = wave * 16 + q * 4;
    #pragma unroll
    for (int nt = 0; nt < NT; ++nt)
        #pragma unroll
        for (int reg = 0; reg < 4; ++reg)
            hL[(lrow + reg) * 65 + nt * 16 + c] = acc[nt][reg];
    __syncthreads();
    #pragma unroll
    for (int it = 0; it < 2; ++it) {
        int id = it * 256 + tid;  // 0..511 = (node 0..63) x (head 0..7)
        int ln = id >> 3, hd = id & 7;
        int gn = blockIdx.x * 64 + ln;
        if (gn >= N) continue;
        const float* hp = &hL[ln * 65 + hd * 8];
        float as = 0.f, ad = 0.f;
        float hv[8];
        #pragma unroll
        for (int j = 0; j < 8; ++j) {
            hv[j] = hp[j];
            as += hv[j] * a_src[hd * 8 + j];
            ad += hv[j] * a_dst[hd * 8 + j];
        }
        adb[gn * 8 + hd] = ad * LOG2E;
        char* r = rec + (size_t)gn * 192;
        unsigned short u[8];
        #pragma unroll
        for (int j = 0; j < 8; ++j) u[j] = f2bf(hv[j]);
        uint4 pk;
        pk.x = (unsigned)u[0] | ((unsigned)u[1] << 16);
        pk.y = (unsigned)u[2] | ((unsigned)u[3] << 16);
        pk.z = (unsigned)u[4] | ((unsigned)u[5] << 16);
        pk.w = (unsigned)u[6] | ((unsigned)u[7] << 16);
        *(uint4*)(r + hd * 16) = pk;
        *(float*)(r + 128 + hd * 4) = as * LOG2E;
    }
}

// =================== plain MFMA GEMM (layer 2, COUT=40) ===================

template <int K, int COUT>
__global__ __launch_bounds__(256) void gemm_mfma_k(
    const float* __restrict__ x, const float* __restrict__ W,
    float* __restrict__ out, int N) {
    constexpr int NT = (COUT + 15) / 16;
    constexpr int KT = K / 32;
    __shared__ alignas(16) short Wf[KT * NT * 64 * 8];
    int tid = threadIdx.x;
    for (int f = tid; f < KT * NT * 64; f += 256) {
        int lane = f & 63;
        int ntk = f >> 6;
        int nt = ntk % NT, kt = ntk / NT;
        int q = lane >> 4, c = lane & 15;
        int n = nt * 16 + c;
        int k0 = kt * 32 + q * 8;
        short8 frag;
        #pragma unroll
        for (int j = 0; j < 8; ++j) {
            float v = (n < COUT) ? W[(size_t)(k0 + j) * COUT + n] : 0.f;
            frag[j] = (short)f2bf(v);
        }
        *(short8*)&Wf[f * 8] = frag;
    }
    __syncthreads();
    int wave = tid >> 6, lane = tid & 63;
    int q = lane >> 4, c = lane & 15;
    int m0 = blockIdx.x * 64 + wave * 16;
    int arow = m0 + c;
    int arl = arow < N ? arow : N - 1;
    f32x4 acc[NT] = {};
    for (int kt = 0; kt < KT; ++kt) {
        const float* xp = x + (size_t)arl * K + kt * 32 + q * 8;
        float4 a0 = *(const float4*)xp;
        float4 a1 = *(const float4*)(xp + 4);
        float av[8] = {a0.x, a0.y, a0.z, a0.w, a1.x, a1.y, a1.z, a1.w};
        short8 af;
        #pragma unroll
        for (int j = 0; j < 8; ++j) af[j] = (short)f2bf(av[j]);
        #pragma unroll
        for (int nt = 0; nt < NT; ++nt) {
            short8 bf = *(const short8*)&Wf[((kt * NT + nt) * 64 + lane) * 8];
            acc[nt] = __builtin_amdgcn_mfma_f32_16x16x32_bf16(af, bf, acc[nt],
                                                              0, 0, 0);
        }
    }
    int orow = m0 + q * 4;
    #pragma unroll
    for (int nt = 0; nt < NT; ++nt) {
        int n = nt * 16 + c;
        if ((COUT % 16) && n >= COUT) continue;
        #pragma unroll
        for (int reg = 0; reg < 4; ++reg) {
            int r = orow + reg;
            if (r < N) out[(size_t)r * COUT + n] = acc[nt][reg];
        }
    }
}

// ======= pack kernel, width 40 (H=1): record 128 B ==========

__global__ __launch_bounds__(256) void pack40_k(
    const float* __restrict__ h, const float* __restrict__ a_src,
    const float* __restrict__ a_dst, char* __restrict__ rec,
    float* __restrict__ adb, int N) {
    int node = blockIdx.x * 4 + (threadIdx.x >> 6);
    if (node >= N) return;
    int lane = threadIdx.x & 63;
    float hv = 0.f, pas = 0.f, pad = 0.f;
    if (lane < 40) {
        hv = h[(size_t)node * 40 + lane];
        pas = hv * a_src[lane];
        pad = hv * a_dst[lane];
    }
    #pragma unroll
    for (int off = 32; off > 0; off >>= 1) {
        pas += __shfl_xor(pas, off);
        pad += __shfl_xor(pad, off);
    }
    char* r = rec + (size_t)node * 128;
    if (lane < 40)
        *(unsigned short*)(r + lane * 2) = f2bf(hv);
    if (lane == 0) {
        *(float*)(r + 80) = pas * LOG2E;
        adb[node] = pad * LOG2E;
    }
}

// ======= single-pass softmax+aggregate, width 64, 8x unroll ======

#define EDGE64(SUF, IDX)                                                     \
    int s##SUF = __builtin_amdgcn_readlane(sv, (IDX));                       \
    const char* r##SUF = rec + (size_t)s##SUF * 192;                         \
    float a##SUF = *(const float*)(r##SUF + hoff);                           \
    unsigned u##SUF = *(const unsigned short*)(r##SUF + lane2);              \
    float v##SUF = a##SUF + ad;                                              \
    v##SUF = fmaxf(v##SUF, NEG_SLOPE * v##SUF);                              \
    float w##SUF = fexp2(v##SUF);

__global__ __launch_bounds__(256) void aggr64_k(
    const char* __restrict__ rec, const float* __restrict__ adb,
    const int* __restrict__ row_ptr, const int* __restrict__ csr_src,
    const float* __restrict__ bias, float* __restrict__ out, int N) {
    int node = blockIdx.x * 4 + (threadIdx.x >> 6);
    if (node >= N) return;
    int lane = threadIdx.x & 63;
    int hd = lane >> 3;
    int lane2 = lane * 2;
    int hoff = 128 + hd * 4;
    int beg = row_ptr[node], end = row_ptr[node + 1];
    float ad = adb[node * 8 + hd];
    float acc0 = 0.f, acc1 = 0.f, acc2 = 0.f, acc3 = 0.f;
    float acc4 = 0.f, acc5 = 0.f, acc6 = 0.f, acc7 = 0.f;
    float l0 = 0.f, l1 = 0.f, l2 = 0.f, l3 = 0.f;
    float l4 = 0.f, l5 = 0.f, l6 = 0.f, l7 = 0.f;
    for (int i0 = beg; i0 < end; i0 += 64) {
        int tail = end - i0;
        int sv = csr_src[i0 + (lane < tail ? lane : 0)];
        int cnt = tail < 64 ? tail : 64;
        int j = 0;
        for (; j + 8 <= cnt; j += 8) {
            EDGE64(A, j)     EDGE64(B, j + 1) EDGE64(C, j + 2) EDGE64(D, j + 3)
            EDGE64(E2, j + 4) EDGE64(F, j + 5) EDGE64(G, j + 6) EDGE64(H2, j + 7)
            l0 += wA; l1 += wB; l2 += wC; l3 += wD;
            l4 += wE2; l5 += wF; l6 += wG; l7 += wH2;
            acc0 = fmaf(wA, __uint_as_float(uA << 16), acc0);
            acc1 = fmaf(wB, __uint_as_float(uB << 16), acc1);
            acc2 = fmaf(wC, __uint_as_float(uC << 16), acc2);
            acc3 = fmaf(wD, __uint_as_float(uD << 16), acc3);
            acc4 = fmaf(wE2, __uint_as_float(uE2 << 16), acc4);
            acc5 = fmaf(wF, __uint_as_float(uF << 16), acc5);
            acc6 = fmaf(wG, __uint_as_float(uG << 16), acc6);
            acc7 = fmaf(wH2, __uint_as_float(uH2 << 16), acc7);
        }
        for (; j + 4 <= cnt; j += 4) {
            EDGE64(A, j) EDGE64(B, j + 1) EDGE64(C, j + 2) EDGE64(D, j + 3)
            l0 += wA; l1 += wB; l2 += wC; l3 += wD;
            acc0 = fmaf(wA, __uint_as_float(uA << 16), acc0);
            acc1 = fmaf(wB, __uint_as_float(uB << 16), acc1);
            acc2 = fmaf(wC, __uint_as_float(uC << 16), acc2);
            acc3 = fmaf(wD, __uint_as_float(uD << 16), acc3);
        }
        for (; j < cnt; ++j) {
            EDGE64(A, j)
            l0 += wA;
            acc0 = fmaf(wA, __uint_as_float(uA << 16), acc0);
        }
    }
    float l = ((l0 + l1) + (l2 + l3)) + ((l4 + l5) + (l6 + l7));
    float acc = ((acc0 + acc1) + (acc2 + acc3)) + ((acc4 + acc5) + (acc6 + acc7));
    out[(size_t)node * 64 + lane] = acc / (l + 1e-16f) + bias[lane];
}

// ======= softmax+aggregate width 40 + fused bias + log_softmax, 8x ======

#define EDGE40(SUF, IDX)                                                     \
    int s##SUF = __builtin_amdgcn_readlane(sv, (IDX));                       \
    const char* r##SUF = rec + (size_t)s##SUF * 128;                         \
    float a##SUF = *(const float*)(r##SUF + 80);                             \
    unsigned u##SUF = *(const unsigned short*)(r##SUF + cl2);                \
    float v##SUF = a##SUF + ad;                                              \
    v##SUF = fmaxf(v##SUF, NEG_SLOPE * v##SUF);                              \
    float w##SUF = fexp2(v##SUF);

__global__ __launch_bounds__(256) void aggr40_k(
    const char* __restrict__ rec, const float* __restrict__ adb,
    const int* __restrict__ row_ptr, const int* __restrict__ csr_src,
    const float* __restrict__ bias, float* __restrict__ out, int N) {
    int node = blockIdx.x * 4 + (threadIdx.x >> 6);
    if (node >= N) return;
    int lane = threadIdx.x & 63;
    int cl2 = (lane < 40 ? lane : 0) * 2;
    int beg = row_ptr[node], end = row_ptr[node + 1];
    float ad = adb[node];
    float acc0 = 0.f, acc1 = 0.f, acc2 = 0.f, acc3 = 0.f;
    float acc4 = 0.f, acc5 = 0.f, acc6 = 0.f, acc7 = 0.f;
    float l0 = 0.f, l1 = 0.f, l2 = 0.f, l3 = 0.f;
    float l4 = 0.f, l5 = 0.f, l6 = 0.f, l7 = 0.f;
    for (int i0 = beg; i0 < end; i0 += 64) {
        int tail = end - i0;
        int sv = csr_src[i0 + (lane < tail ? lane : 0)];
        int cnt = tail < 64 ? tail : 64;
        int j = 0;
        for (; j + 8 <= cnt; j += 8) {
            EDGE40(A, j)     EDGE40(B, j + 1) EDGE40(C, j + 2) EDGE40(D, j + 3)
            EDGE40(E2, j + 4) EDGE40(F, j + 5) EDGE40(G, j + 6) EDGE40(H2, j + 7)
            l0 += wA; l1 += wB; l2 += wC; l3 += wD;
            l4 += wE2; l5 += wF; l6 += wG; l7 += wH2;
            acc0 = fmaf(wA, __uint_as_float(uA << 16), acc0);
            acc1 = fmaf(wB, __uint_as_float(uB << 16), acc1);
            acc2 = fmaf(wC, __uint_as_float(uC << 16), acc2);
            acc3 = fmaf(wD, __uint_as_float(uD << 16), acc3);
            acc4 = fmaf(wE2, __uint_as_float(uE2 << 16), acc4);
            acc5 = fmaf(wF, __uint_as_float(uF << 16), acc5);
            acc6 = fmaf(wG, __uint_as_float(uG << 16), acc6);
            acc7 = fmaf(wH2, __uint_as_float(uH2 << 16), acc7);
        }
        for (; j + 4 <= cnt; j += 4) {
            EDGE40(A, j) EDGE40(B, j + 1) EDGE40(C, j + 2) EDGE40(D, j + 3)
            l0 += wA; l1 += wB; l2 += wC; l3 += wD;
            acc0 = fmaf(wA, __uint_as_float(uA << 16), acc0);
            acc1 = fmaf(wB, __uint_as_float(uB << 16), acc1);
            acc2 = fmaf(wC, __uint_as_float(uC << 16), acc2);
            acc3 = fmaf(wD, __uint_as_float(uD << 16), acc3);
        }
        for (; j < cnt; ++j) {
            EDGE40(A, j)
            l0 += wA;
            acc0 = fmaf(wA, __uint_as_float(uA << 16), acc0);
        }
    }
    float l = ((l0 + l1) + (l2 + l3)) + ((l4 + l5) + (l6 + l7));
    float acc = ((acc0 + acc1) + (acc2 + acc3)) + ((acc4 + acc5) + (acc6 + acc7));
    // fused bias + log_softmax over the 40 class lanes
    float val = acc / (l + 1e-16f) + ((lane < 40) ? bias[lane] : 0.f);
    float mval = (lane < 40) ? val : -1e30f;
    #pragma unroll
    for (int off = 32; off > 0; off >>= 1)
        mval = fmaxf(mval, __shfl_xor(mval, off));
    float ex = (lane < 40) ? __expf(val - mval) : 0.f;
    #pragma unroll
    for (int off = 32; off > 0; off >>= 1) ex += __shfl_xor(ex, off);
    if (lane < 40)
        out[(size_t)node * 40 + lane] = val - mval - __logf(ex);
}

// =================== launch ===================

extern "C" void kernel_launch(void* const* d_in, const int* in_sizes, int n_in,
                              void* d_out, int out_size, void* d_ws,
                              size_t ws_size, hipStream_t stream) {
    const float* features = (const float*)d_in[0];
    const int* edge_index = (const int*)d_in[1];
    const float* W0 = (const float*)d_in[2];
    const float* as0 = (const float*)d_in[3];
    const float* ad0 = (const float*)d_in[4];
    const float* b0 = (const float*)d_in[5];
    const float* W1 = (const float*)d_in[6];
    const float* as1 = (const float*)d_in[7];
    const float* ad1 = (const float*)d_in[8];
    const float* b1 = (const float*)d_in[9];
    const float* W2 = (const float*)d_in[10];
    const float* as2 = (const float*)d_in[11];
    const float* ad2 = (const float*)d_in[12];
    const float* b2 = (const float*)d_in[13];

    int N = in_sizes[0] / 256;
    int E = in_sizes[1] / 2;
    int Etot = E + N;
    int nbuck = (N + 255) >> 8;
    const int* srcs = edge_index;
    const int* dsts = edge_index + E;

    // workspace layout
    float* ws = (float*)d_ws;
    float* Hbuf = ws;                              // N*64 floats (pairs / h2)
    float* Abuf = Hbuf + (size_t)N * 64;           // N*64 floats
    float* adb  = Abuf + (size_t)N * 64;           // N*8
    char* recbuf = (char*)(adb + (size_t)N * 8);   // N*192 bytes
    int* row_ptr = (int*)(recbuf + (size_t)N * 192); // N+1
    int* bcnt    = row_ptr + (N + 2);              // 512
    int* bptr    = bcnt + 512;                     // 513
    int* bcur    = bptr + 513;                     // 512
    int* csr_src = bcur + 512;                     // Etot
    int2* pairs  = (int2*)Hbuf;                    // scratch, dead before gemm

    const int B = 256;
    int gAg = (N + 3) / 4;
    int gBk = (Etot + EPB - 1) / EPB;
    int gGm = (N + 63) / 64;

    // ---------- CSR build ----------
    (void)hipMemsetAsync(bcnt, 0, 512 * 4, stream);
    bucket_hist_k<<<gBk, B, 0, stream>>>(dsts, bcnt, E, Etot, nbuck);
    bucket_scan_k<<<1, 512, 0, stream>>>(bcnt, bptr, bcur, nbuck, Etot);
    bucket_scatter_k<<<gBk, B, 0, stream>>>(srcs, dsts, bcur, pairs, E, Etot,
                                            nbuck);
    bucket_sort_k<<<nbuck, B, 0, stream>>>(pairs, bptr, row_ptr, csr_src, N,
                                           Etot, nbuck);

    // ---------------- layer 0 ----------------
    gemm_pack8_k<256><<<gGm, B, 0, stream>>>(features, W0, as0, ad0, recbuf,
                                             adb, N);
    aggr64_k<<<gAg, B, 0, stream>>>(recbuf, adb, row_ptr, csr_src, b0, Abuf,
                                    N);

    // ---------------- layer 1 ----------------
    gemm_pack8_k<64><<<gGm, B, 0, stream>>>(Abuf, W1, as1, ad1, recbuf, adb,
                                            N);
    aggr64_k<<<gAg, B, 0, stream>>>(recbuf, adb, row_ptr, csr_src, b1, Abuf,
                                    N);

    // ---------------- layer 2 ----------------
    gemm_mfma_k<64, 40><<<gGm, B, 0, stream>>>(Abuf, W2, Hbuf, N);
    pack40_k<<<gAg, B, 0, stream>>>(Hbuf, as2, ad2, recbuf, adb, N);
    aggr40_k<<<gAg, B, 0, stream>>>(recbuf, adb, row_ptr, csr_src, b2,
                                    (float*)d_out, N);
}

// Round 14
// 651.001 us; speedup vs baseline: 1.8802x; 1.0455x over previous
//
#include <hip/hip_runtime.h>
#include <hip/hip_bf16.h>

#define NEG_SLOPE 0.2f
#define LOG2E 1.44269504f
#define EPB 4096  // edges per block in bucket phases

typedef __attribute__((ext_vector_type(8))) short short8;
typedef __attribute__((ext_vector_type(4))) float f32x4;

__device__ __forceinline__ unsigned short f2bf(float x) {
    unsigned u = __float_as_uint(x);
    unsigned r = (u + 0x7FFFu + ((u >> 16) & 1u)) >> 16;  // RNE
    return (unsigned short)r;
}

__device__ __forceinline__ float fexp2(float x) {
    return __builtin_amdgcn_exp2f(x);  // v_exp_f32: 2^x
}

__device__ __forceinline__ float readlane_f(float v, int l) {
    return __int_as_float(__builtin_amdgcn_readlane(__float_as_int(v), l));
}

// =================== CSR build: two-level counting sort ===================

__global__ __launch_bounds__(256) void bucket_hist_k(
    const int* __restrict__ dsts, int* __restrict__ bcnt, int E, int Etot,
    int nbuck) {
    __shared__ int lh[512];
    for (int i = threadIdx.x; i < nbuck; i += 256) lh[i] = 0;
    __syncthreads();
    int base = blockIdx.x * EPB;
    int cnt = Etot - base;
    if (cnt > EPB) cnt = EPB;
    for (int i = threadIdx.x; i < cnt; i += 256) {
        int e = base + i;
        int d = (e < E) ? dsts[e] : (e - E);
        atomicAdd(&lh[d >> 8], 1);
    }
    __syncthreads();
    for (int i = threadIdx.x; i < nbuck; i += 256) {
        int c = lh[i];
        if (c) atomicAdd(&bcnt[i], c);
    }
}

__global__ __launch_bounds__(512) void bucket_scan_k(
    const int* __restrict__ bcnt, int* __restrict__ bptr,
    int* __restrict__ bcur, int nbuck, int Etot) {
    __shared__ int tmp[512];
    int t = threadIdx.x;
    int v = (t < nbuck) ? bcnt[t] : 0;
    tmp[t] = v;
    __syncthreads();
    for (int off = 1; off < 512; off <<= 1) {
        int x = (t >= off) ? tmp[t - off] : 0;
        __syncthreads();
        tmp[t] += x;
        __syncthreads();
    }
    int excl = tmp[t] - v;
    if (t < nbuck) { bptr[t] = excl; bcur[t] = excl; }
    if (t == 0) bptr[nbuck] = Etot;
}

__global__ __launch_bounds__(256) void bucket_scatter_k(
    const int* __restrict__ srcs, const int* __restrict__ dsts,
    int* __restrict__ bcur, int2* __restrict__ pairs, int E, int Etot,
    int nbuck) {
    __shared__ int lh[512];
    __shared__ int lbase[512];
    for (int i = threadIdx.x; i < nbuck; i += 256) lh[i] = 0;
    __syncthreads();
    int base = blockIdx.x * EPB;
    int cnt = Etot - base;
    if (cnt > EPB) cnt = EPB;
    for (int i = threadIdx.x; i < cnt; i += 256) {
        int e = base + i;
        int d = (e < E) ? dsts[e] : (e - E);
        atomicAdd(&lh[d >> 8], 1);
    }
    __syncthreads();
    for (int i = threadIdx.x; i < nbuck; i += 256) {
        int c = lh[i];
        lbase[i] = c ? atomicAdd(&bcur[i], c) : 0;
    }
    __syncthreads();
    for (int i = threadIdx.x; i < nbuck; i += 256) lh[i] = 0;
    __syncthreads();
    for (int i = threadIdx.x; i < cnt; i += 256) {
        int e = base + i;
        int s, d;
        if (e < E) { s = srcs[e]; d = dsts[e]; }
        else       { s = e - E;   d = s; }
        int b = d >> 8;
        int off = atomicAdd(&lh[b], 1);
        pairs[lbase[b] + off] = make_int2(s, d);
    }
}

__global__ __launch_bounds__(256) void bucket_sort_k(
    const int2* __restrict__ pairs, const int* __restrict__ bptr,
    int* __restrict__ row_ptr, int* __restrict__ csr_src, int N, int Etot,
    int nbuck) {
    __shared__ int lh[256];
    __shared__ int lscan[256];
    int b = blockIdx.x;
    int n0 = b << 8;
    int e0 = bptr[b], e1 = bptr[b + 1];
    int t = threadIdx.x;
    lh[t] = 0;
    __syncthreads();
    for (int e = e0 + t; e < e1; e += 256)
        atomicAdd(&lh[pairs[e].y - n0], 1);
    __syncthreads();
    int v = lh[t];
    lscan[t] = v;
    __syncthreads();
    for (int off = 1; off < 256; off <<= 1) {
        int x = (t >= off) ? lscan[t - off] : 0;
        __syncthreads();
        lscan[t] += x;
        __syncthreads();
    }
    int start = e0 + lscan[t] - v;
    int n = n0 + t;
    if (n < N) row_ptr[n] = start;
    lh[t] = start;  // reuse as cursor
    __syncthreads();
    for (int e = e0 + t; e < e1; e += 256) {
        int2 p = pairs[e];
        int pos = atomicAdd(&lh[p.y - n0], 1);
        csr_src[pos] = p.x;
    }
    if (b == nbuck - 1 && t == 0) row_ptr[N] = Etot;
}

// ====== fused MFMA GEMM + pack8 (COUT=64): x[N,K] @ W[K,64] -> records =====

template <int K>
__global__ __launch_bounds__(256) void gemm_pack8_k(
    const float* __restrict__ x, const float* __restrict__ W,
    const float* __restrict__ a_src, const float* __restrict__ a_dst,
    char* __restrict__ rec, float* __restrict__ adb, int N) {
    constexpr int NT = 4;
    constexpr int KT = K / 32;
    constexpr size_t WF_BYTES = (size_t)KT * NT * 64 * 8 * sizeof(short);
    constexpr size_t H_BYTES = (size_t)64 * 65 * sizeof(float);
    __shared__ alignas(16) char smem[WF_BYTES > H_BYTES ? WF_BYTES : H_BYTES];
    short* Wf = (short*)smem;
    float* hL = (float*)smem;
    int tid = threadIdx.x;
    for (int f = tid; f < KT * NT * 64; f += 256) {
        int lane = f & 63;
        int ntk = f >> 6;
        int nt = ntk % NT, kt = ntk / NT;
        int q = lane >> 4, c = lane & 15;
        int n = nt * 16 + c;
        int k0 = kt * 32 + q * 8;
        short8 frag;
        #pragma unroll
        for (int j = 0; j < 8; ++j)
            frag[j] = (short)f2bf(W[(size_t)(k0 + j) * 64 + n]);
        *(short8*)&Wf[f * 8] = frag;
    }
    __syncthreads();
    int wave = tid >> 6, lane = tid & 63;
    int q = lane >> 4, c = lane & 15;
    int m0 = blockIdx.x * 64 + wave * 16;
    int arow = m0 + c;
    int arl = arow < N ? arow : N - 1;
    f32x4 acc[NT] = {};
    for (int kt = 0; kt < KT; ++kt) {
        const float* xp = x + (size_t)arl * K + kt * 32 + q * 8;
        float4 a0 = *(const float4*)xp;
        float4 a1 = *(const float4*)(xp + 4);
        float av[8] = {a0.x, a0.y, a0.z, a0.w, a1.x, a1.y, a1.z, a1.w};
        short8 af;
        #pragma unroll
        for (int j = 0; j < 8; ++j) af[j] = (short)f2bf(av[j]);
        #pragma unroll
        for (int nt = 0; nt < NT; ++nt) {
            short8 bf = *(const short8*)&Wf[((kt * NT + nt) * 64 + lane) * 8];
            acc[nt] = __builtin_amdgcn_mfma_f32_16x16x32_bf16(af, bf, acc[nt],
                                                              0, 0, 0);
        }
    }
    __syncthreads();  // all waves done reading Wf; reuse as hL
    int lrow = wave * 16 + q * 4;
    #pragma unroll
    for (int nt = 0; nt < NT; ++nt)
        #pragma unroll
        for (int reg = 0; reg < 4; ++reg)
            hL[(lrow + reg) * 65 + nt * 16 + c] = acc[nt][reg];
    __syncthreads();
    #pragma unroll
    for (int it = 0; it < 2; ++it) {
        int id = it * 256 + tid;  // 0..511 = (node 0..63) x (head 0..7)
        int ln = id >> 3, hd = id & 7;
        int gn = blockIdx.x * 64 + ln;
        if (gn >= N) continue;
        const float* hp = &hL[ln * 65 + hd * 8];
        float as = 0.f, ad = 0.f;
        float hv[8];
        #pragma unroll
        for (int j = 0; j < 8; ++j) {
            hv[j] = hp[j];
            as += hv[j] * a_src[hd * 8 + j];
            ad += hv[j] * a_dst[hd * 8 + j];
        }
        adb[gn * 8 + hd] = ad * LOG2E;
        char* r = rec + (size_t)gn * 192;
        unsigned short u[8];
        #pragma unroll
        for (int j = 0; j < 8; ++j) u[j] = f2bf(hv[j]);
        uint4 pk;
        pk.x = (unsigned)u[0] | ((unsigned)u[1] << 16);
        pk.y = (unsigned)u[2] | ((unsigned)u[3] << 16);
        pk.z = (unsigned)u[4] | ((unsigned)u[5] << 16);
        pk.w = (unsigned)u[6] | ((unsigned)u[7] << 16);
        *(uint4*)(r + hd * 16) = pk;
        *(float*)(r + 128 + hd * 4) = as * LOG2E;
    }
}

// ====== fused MFMA GEMM + pack40 (layer 2, COUT=40) -> 128 B records ======

__global__ __launch_bounds__(256) void gemm_pack40_k(
    const float* __restrict__ x, const float* __restrict__ W,
    const float* __restrict__ a_src, const float* __restrict__ a_dst,
    char* __restrict__ rec, float* __restrict__ adb, int N) {
    constexpr int K = 64, NT = 3, KT = 2;
    constexpr size_t WF_BYTES = (size_t)KT * NT * 64 * 8 * sizeof(short);
    constexpr size_t H_BYTES = (size_t)64 * 41 * sizeof(float);
    __shared__ alignas(16) char smem[WF_BYTES > H_BYTES ? WF_BYTES : H_BYTES];
    short* Wf = (short*)smem;
    float* hL = (float*)smem;
    int tid = threadIdx.x;
    for (int f = tid; f < KT * NT * 64; f += 256) {
        int lane = f & 63;
        int ntk = f >> 6;
        int nt = ntk % NT, kt = ntk / NT;
        int q = lane >> 4, c = lane & 15;
        int n = nt * 16 + c;
        int k0 = kt * 32 + q * 8;
        short8 frag;
        #pragma unroll
        for (int j = 0; j < 8; ++j) {
            float v = (n < 40) ? W[(size_t)(k0 + j) * 40 + n] : 0.f;
            frag[j] = (short)f2bf(v);
        }
        *(short8*)&Wf[f * 8] = frag;
    }
    __syncthreads();
    int wave = tid >> 6, lane = tid & 63;
    int q = lane >> 4, c = lane & 15;
    int m0 = blockIdx.x * 64 + wave * 16;
    int arow = m0 + c;
    int arl = arow < N ? arow : N - 1;
    f32x4 acc[NT] = {};
    for (int kt = 0; kt < KT; ++kt) {
        const float* xp = x + (size_t)arl * K + kt * 32 + q * 8;
        float4 a0 = *(const float4*)xp;
        float4 a1 = *(const float4*)(xp + 4);
        float av[8] = {a0.x, a0.y, a0.z, a0.w, a1.x, a1.y, a1.z, a1.w};
        short8 af;
        #pragma unroll
        for (int j = 0; j < 8; ++j) af[j] = (short)f2bf(av[j]);
        #pragma unroll
        for (int nt = 0; nt < NT; ++nt) {
            short8 bf = *(const short8*)&Wf[((kt * NT + nt) * 64 + lane) * 8];
            acc[nt] = __builtin_amdgcn_mfma_f32_16x16x32_bf16(af, bf, acc[nt],
                                                              0, 0, 0);
        }
    }
    __syncthreads();
    int lrow = wave * 16 + q * 4;
    #pragma unroll
    for (int nt = 0; nt < NT; ++nt) {
        int n = nt * 16 + c;
        if (n >= 40) continue;
        #pragma unroll
        for (int reg = 0; reg < 4; ++reg)
            hL[(lrow + reg) * 41 + n] = acc[nt][reg];
    }
    __syncthreads();
    // 4 threads per node compute pas/pad
    int ln = tid >> 2, sub = tid & 3;
    int gn = blockIdx.x * 64 + ln;
    float pas = 0.f, pad = 0.f;
    if (gn < N) {
        for (int j = sub; j < 40; j += 4) {
            float hv = hL[ln * 41 + j];
            pas += hv * a_src[j];
            pad += hv * a_dst[j];
        }
    }
    pas += __shfl_xor(pas, 1); pas += __shfl_xor(pas, 2);
    pad += __shfl_xor(pad, 1); pad += __shfl_xor(pad, 2);
    if (gn < N && sub == 0) {
        *(float*)(rec + (size_t)gn * 128 + 80) = pas * LOG2E;
        adb[gn] = pad * LOG2E;
    }
    // write bf16 h
    for (int i = tid; i < 64 * 40; i += 256) {
        int n2 = i / 40, ch = i % 40;
        int g2 = blockIdx.x * 64 + n2;
        if (g2 < N)
            *(unsigned short*)(rec + (size_t)g2 * 128 + ch * 2) =
                f2bf(hL[n2 * 41 + ch]);
    }
}

// ======= single-pass softmax+aggregate, width 64, 8x unroll ======

#define EDGE64(SUF, IDX)                                                     \
    int s##SUF = __builtin_amdgcn_readlane(sv, (IDX));                       \
    const char* r##SUF = rec + (size_t)s##SUF * 192;                         \
    float a##SUF = *(const float*)(r##SUF + hoff);                           \
    unsigned u##SUF = *(const unsigned short*)(r##SUF + lane2);              \
    float v##SUF = a##SUF + ad;                                              \
    v##SUF = fmaxf(v##SUF, NEG_SLOPE * v##SUF);                              \
    float w##SUF = fexp2(v##SUF);

__global__ __launch_bounds__(256) void aggr64_k(
    const char* __restrict__ rec, const float* __restrict__ adb,
    const int* __restrict__ row_ptr, const int* __restrict__ csr_src,
    const float* __restrict__ bias, float* __restrict__ out, int N) {
    int node = blockIdx.x * 4 + (threadIdx.x >> 6);
    if (node >= N) return;
    int lane = threadIdx.x & 63;
    int hd = lane >> 3;
    int lane2 = lane * 2;
    int hoff = 128 + hd * 4;
    int beg = row_ptr[node], end = row_ptr[node + 1];
    float ad = adb[node * 8 + hd];
    float acc0 = 0.f, acc1 = 0.f, acc2 = 0.f, acc3 = 0.f;
    float acc4 = 0.f, acc5 = 0.f, acc6 = 0.f, acc7 = 0.f;
    float l0 = 0.f, l1 = 0.f, l2 = 0.f, l3 = 0.f;
    float l4 = 0.f, l5 = 0.f, l6 = 0.f, l7 = 0.f;
    for (int i0 = beg; i0 < end; i0 += 64) {
        int tail = end - i0;
        int sv = csr_src[i0 + (lane < tail ? lane : 0)];
        int cnt = tail < 64 ? tail : 64;
        int j = 0;
        for (; j + 8 <= cnt; j += 8) {
            EDGE64(A, j)     EDGE64(B, j + 1) EDGE64(C, j + 2) EDGE64(D, j + 3)
            EDGE64(E2, j + 4) EDGE64(F, j + 5) EDGE64(G, j + 6) EDGE64(H2, j + 7)
            l0 += wA; l1 += wB; l2 += wC; l3 += wD;
            l4 += wE2; l5 += wF; l6 += wG; l7 += wH2;
            acc0 = fmaf(wA, __uint_as_float(uA << 16), acc0);
            acc1 = fmaf(wB, __uint_as_float(uB << 16), acc1);
            acc2 = fmaf(wC, __uint_as_float(uC << 16), acc2);
            acc3 = fmaf(wD, __uint_as_float(uD << 16), acc3);
            acc4 = fmaf(wE2, __uint_as_float(uE2 << 16), acc4);
            acc5 = fmaf(wF, __uint_as_float(uF << 16), acc5);
            acc6 = fmaf(wG, __uint_as_float(uG << 16), acc6);
            acc7 = fmaf(wH2, __uint_as_float(uH2 << 16), acc7);
        }
        for (; j + 4 <= cnt; j += 4) {
            EDGE64(A, j) EDGE64(B, j + 1) EDGE64(C, j + 2) EDGE64(D, j + 3)
            l0 += wA; l1 += wB; l2 += wC; l3 += wD;
            acc0 = fmaf(wA, __uint_as_float(uA << 16), acc0);
            acc1 = fmaf(wB, __uint_as_float(uB << 16), acc1);
            acc2 = fmaf(wC, __uint_as_float(uC << 16), acc2);
            acc3 = fmaf(wD, __uint_as_float(uD << 16), acc3);
        }
        for (; j < cnt; ++j) {
            EDGE64(A, j)
            l0 += wA;
            acc0 = fmaf(wA, __uint_as_float(uA << 16), acc0);
        }
    }
    float l = ((l0 + l1) + (l2 + l3)) + ((l4 + l5) + (l6 + l7));
    float acc = ((acc0 + acc1) + (acc2 + acc3)) + ((acc4 + acc5) + (acc6 + acc7));
    out[(size_t)node * 64 + lane] = acc / (l + 1e-16f) + bias[lane];
}

// ======= aggr40: parallel weight phase (1 exp / 64 edges) + readlane fma ====

#define F40(SUF, IDX)                                                        \
    int s##SUF = __builtin_amdgcn_readlane(sv, (IDX));                       \
    float w##SUF = readlane_f(wv, (IDX));                                    \
    unsigned u##SUF =                                                        \
        *(const unsigned short*)(rec + (size_t)s##SUF * 128 + cl2);

__global__ __launch_bounds__(256) void aggr40_k(
    const char* __restrict__ rec, const float* __restrict__ adb,
    const int* __restrict__ row_ptr, const int* __restrict__ csr_src,
    const float* __restrict__ bias, float* __restrict__ out, int N) {
    int node = blockIdx.x * 4 + (threadIdx.x >> 6);
    if (node >= N) return;
    int lane = threadIdx.x & 63;
    int cl2 = (lane < 40 ? lane : 0) * 2;
    int beg = row_ptr[node], end = row_ptr[node + 1];
    float ad = adb[node];
    float acc0 = 0.f, acc1 = 0.f, acc2 = 0.f, acc3 = 0.f;
    float acc4 = 0.f, acc5 = 0.f, acc6 = 0.f, acc7 = 0.f;
    float lpart = 0.f;
    for (int i0 = beg; i0 < end; i0 += 64) {
        int tail = end - i0;
        int sv = csr_src[i0 + (lane < tail ? lane : 0)];
        int cnt = tail < 64 ? tail : 64;
        // ---- parallel weight phase: lane computes its own edge's weight ----
        float as = *(const float*)(rec + (size_t)sv * 128 + 80);
        float v = as + ad;
        v = fmaxf(v, NEG_SLOPE * v);
        float wv = fexp2(v);
        wv = (lane < cnt) ? wv : 0.f;
        lpart += wv;
        // ---- fma phase: branch-free, weights via readlane ----
        int j = 0;
        for (; j + 8 <= cnt; j += 8) {
            F40(A, j)     F40(B, j + 1) F40(C, j + 2) F40(D, j + 3)
            F40(E2, j + 4) F40(F, j + 5) F40(G, j + 6) F40(H2, j + 7)
            acc0 = fmaf(wA, __uint_as_float(uA << 16), acc0);
            acc1 = fmaf(wB, __uint_as_float(uB << 16), acc1);
            acc2 = fmaf(wC, __uint_as_float(uC << 16), acc2);
            acc3 = fmaf(wD, __uint_as_float(uD << 16), acc3);
            acc4 = fmaf(wE2, __uint_as_float(uE2 << 16), acc4);
            acc5 = fmaf(wF, __uint_as_float(uF << 16), acc5);
            acc6 = fmaf(wG, __uint_as_float(uG << 16), acc6);
            acc7 = fmaf(wH2, __uint_as_float(uH2 << 16), acc7);
        }
        for (; j + 4 <= cnt; j += 4) {
            F40(A, j) F40(B, j + 1) F40(C, j + 2) F40(D, j + 3)
            acc0 = fmaf(wA, __uint_as_float(uA << 16), acc0);
            acc1 = fmaf(wB, __uint_as_float(uB << 16), acc1);
            acc2 = fmaf(wC, __uint_as_float(uC << 16), acc2);
            acc3 = fmaf(wD, __uint_as_float(uD << 16), acc3);
        }
        for (; j < cnt; ++j) {
            F40(A, j)
            acc0 = fmaf(wA, __uint_as_float(uA << 16), acc0);
        }
    }
    // reduce l across all lanes (each lane holds partial sum of its edges)
    #pragma unroll
    for (int off = 32; off > 0; off >>= 1) lpart += __shfl_xor(lpart, off);
    float l = lpart;
    float acc = ((acc0 + acc1) + (acc2 + acc3)) + ((acc4 + acc5) + (acc6 + acc7));
    // fused bias + log_softmax over the 40 class lanes
    float val = acc / (l + 1e-16f) + ((lane < 40) ? bias[lane] : 0.f);
    float mval = (lane < 40) ? val : -1e30f;
    #pragma unroll
    for (int off = 32; off > 0; off >>= 1)
        mval = fmaxf(mval, __shfl_xor(mval, off));
    float ex = (lane < 40) ? __expf(val - mval) : 0.f;
    #pragma unroll
    for (int off = 32; off > 0; off >>= 1) ex += __shfl_xor(ex, off);
    if (lane < 40)
        out[(size_t)node * 40 + lane] = val - mval - __logf(ex);
}

// =================== launch ===================

extern "C" void kernel_launch(void* const* d_in, const int* in_sizes, int n_in,
                              void* d_out, int out_size, void* d_ws,
                              size_t ws_size, hipStream_t stream) {
    const float* features = (const float*)d_in[0];
    const int* edge_index = (const int*)d_in[1];
    const float* W0 = (const float*)d_in[2];
    const float* as0 = (const float*)d_in[3];
    const float* ad0 = (const float*)d_in[4];
    const float* b0 = (const float*)d_in[5];
    const float* W1 = (const float*)d_in[6];
    const float* as1 = (const float*)d_in[7];
    const float* ad1 = (const float*)d_in[8];
    const float* b1 = (const float*)d_in[9];
    const float* W2 = (const float*)d_in[10];
    const float* as2 = (const float*)d_in[11];
    const float* ad2 = (const float*)d_in[12];
    const float* b2 = (const float*)d_in[13];

    int N = in_sizes[0] / 256;
    int E = in_sizes[1] / 2;
    int Etot = E + N;
    int nbuck = (N + 255) >> 8;
    const int* srcs = edge_index;
    const int* dsts = edge_index + E;

    // workspace layout
    float* ws = (float*)d_ws;
    float* Hbuf = ws;                              // N*64 floats (pairs)
    float* Abuf = Hbuf + (size_t)N * 64;           // N*64 floats
    float* adb  = Abuf + (size_t)N * 64;           // N*8
    char* recbuf = (char*)(adb + (size_t)N * 8);   // N*192 bytes
    int* row_ptr = (int*)(recbuf + (size_t)N * 192); // N+1
    int* bcnt    = row_ptr + (N + 2);              // 512
    int* bptr    = bcnt + 512;                     // 513
    int* bcur    = bptr + 513;                     // 512
    int* csr_src = bcur + 512;                     // Etot
    int2* pairs  = (int2*)Hbuf;                    // scratch, dead before gemm

    const int B = 256;
    int gAg = (N + 3) / 4;
    int gBk = (Etot + EPB - 1) / EPB;
    int gGm = (N + 63) / 64;

    // ---------- CSR build ----------
    (void)hipMemsetAsync(bcnt, 0, 512 * 4, stream);
    bucket_hist_k<<<gBk, B, 0, stream>>>(dsts, bcnt, E, Etot, nbuck);
    bucket_scan_k<<<1, 512, 0, stream>>>(bcnt, bptr, bcur, nbuck, Etot);
    bucket_scatter_k<<<gBk, B, 0, stream>>>(srcs, dsts, bcur, pairs, E, Etot,
                                            nbuck);
    bucket_sort_k<<<nbuck, B, 0, stream>>>(pairs, bptr, row_ptr, csr_src, N,
                                           Etot, nbuck);

    // ---------------- layer 0 ----------------
    gemm_pack8_k<256><<<gGm, B, 0, stream>>>(features, W0, as0, ad0, recbuf,
                                             adb, N);
    aggr64_k<<<gAg, B, 0, stream>>>(recbuf, adb, row_ptr, csr_src, b0, Abuf,
                                    N);

    // ---------------- layer 1 ----------------
    gemm_pack8_k<64><<<gGm, B, 0, stream>>>(Abuf, W1, as1, ad1, recbuf, adb,
                                            N);
    aggr64_k<<<gAg, B, 0, stream>>>(recbuf, adb, row_ptr, csr_src, b1, Abuf,
                                    N);

    // ---------------- layer 2 ----------------
    gemm_pack40_k<<<gGm, B, 0, stream>>>(Abuf, W2, as2, ad2, recbuf, adb, N);
    aggr40_k<<<gAg, B, 0, stream>>>(recbuf, adb, row_ptr, csr_src, b2,
                                    (float*)d_out, N);
}